// Round 23
// baseline (1285.980 us; speedup 1.0000x reference)
//
#include <hip/hip_runtime.h>
#include <hip/hip_bf16.h>

#define BS 4
#define SEQL 2048
#define DM 512
#define DIN 1024
#define NH 16
#define HD 64
#define DST 64
#define NC 8
#define CKS 256
#define DIP 2192
#define CVD 1152
#define NROWS (BS*SEQL)          /* 8192 */
#define NTOK (BS*SEQL*DM)        /* 4194304 */

typedef unsigned short u16;
typedef __bf16 bf16x8 __attribute__((ext_vector_type(8)));
typedef float f32x4 __attribute__((ext_vector_type(4)));

__device__ __forceinline__ u16 cvt_bf16(float f){
  unsigned int x = __float_as_uint(f);
  unsigned int r = x + 0x7fffu + ((x>>16)&1u);
  return (u16)(r>>16);
}
__device__ __forceinline__ float bf2f(u16 u){
  return __uint_as_float(((unsigned int)u)<<16);
}

// ---------------- elementwise (proven) ----------------
__global__ void k_add_flip(float* __restrict__ dst, const float* __restrict__ src, int flip){
  int i = blockIdx.x*256 + threadIdx.x;
  if(i >= NTOK) return;
  int d = i & (DM-1);
  int l = (i >> 9) & (SEQL-1);
  int b = i >> 20;
  int sl = flip ? (SEQL-1-l) : l;
  dst[i] += src[(b*SEQL + sl)*DM + d];
}

__global__ void k_flip(float* __restrict__ dst, const float* __restrict__ src){
  int i = blockIdx.x*256 + threadIdx.x;
  if(i >= NTOK) return;
  int d = i & (DM-1);
  int l = (i >> 9) & (SEQL-1);
  int b = i >> 20;
  dst[i] = src[(b*SEQL + (SEQL-1-l))*DM + d];
}

// f32 -> bf16 (verified round-8)
__global__ void k_cvt(const float* __restrict__ src, u16* __restrict__ dst, int n4){
  int i = blockIdx.x*256 + threadIdx.x;
  if(i >= n4) return;
  float4 f = reinterpret_cast<const float4*>(src)[i];
  ushort4 o; o.x=cvt_bf16(f.x); o.y=cvt_bf16(f.y); o.z=cvt_bf16(f.z); o.w=cvt_bf16(f.w);
  reinterpret_cast<ushort4*>(dst)[i] = o;
}

__global__ void k_ln(const float* __restrict__ X, const float* __restrict__ w,
                     const float* __restrict__ bb, float* __restrict__ O){
  int row = blockIdx.x, tid = threadIdx.x;
  const float* x = X + (size_t)row*DM;
  float* o = O + (size_t)row*DM;
  float s=0.f, s2=0.f;
  for(int j=tid;j<DM;j+=256){ float v=x[j]; s+=v; s2+=v*v; }
  __shared__ float r1[256], r2[256];
  r1[tid]=s; r2[tid]=s2; __syncthreads();
  for(int off=128;off>0;off>>=1){
    if(tid<off){ r1[tid]+=r1[tid+off]; r2[tid]+=r2[tid+off]; }
    __syncthreads();
  }
  float m = r1[0]*(1.f/DM);
  float var = r2[0]*(1.f/DM) - m*m;
  float inv = rsqrtf(var + 1e-5f);
  for(int j=tid;j<DM;j+=256) o[j] = (x[j]-m)*inv*w[j] + bb[j];
}

// RMSNorm reading Y f32, writing bf16 only
__global__ void k_rmsb(const float* __restrict__ Y, const float* __restrict__ gw,
                       u16* __restrict__ Obf){
  int row = blockIdx.x, tid = threadIdx.x;
  const float* y = Y + (size_t)row*DIN;
  float ss=0.f;
  for(int j=tid;j<DIN;j+=256){ float v=y[j]; ss+=v*v; }
  __shared__ float red[256];
  red[tid]=ss; __syncthreads();
  for(int off=128;off>0;off>>=1){
    if(tid<off) red[tid]+=red[tid+off];
    __syncthreads();
  }
  float inv = rsqrtf(red[0]*(1.f/DIN) + 1e-5f);
  for(int j=tid;j<DIN;j+=256) Obf[(size_t)row*DIN + j] = cvt_bf16(y[j]*inv*gw[j]);
}

// dec2
__global__ void k_dec2(const float* __restrict__ D1, const float* __restrict__ w,
                       const float* __restrict__ bb, float* __restrict__ out){
  int row = blockIdx.x, tid = threadIdx.x;
  int lane = tid & 63, wave = tid >> 6;
  const float* x = D1 + (size_t)row*1024;
  float acc[10];
  #pragma unroll
  for(int o=0;o<10;o++) acc[o]=0.f;
  for(int j=tid;j<1024;j+=256){
    float v = x[j];
    const float* wr = w + (size_t)j*10;
    #pragma unroll
    for(int o=0;o<10;o++) acc[o] += v*wr[o];
  }
  __shared__ float red[4][10];
  #pragma unroll
  for(int o=0;o<10;o++){
    float v = acc[o];
    #pragma unroll
    for(int s=32;s>0;s>>=1) v += __shfl_down(v, s, 64);
    if(lane==0) red[wave][o] = v;
  }
  __syncthreads();
  if(tid < 10)
    out[(size_t)row*10 + tid] = red[0][tid]+red[1][tid]+red[2][tid]+red[3][tid] + bb[tid];
}

// transpose-convert with explicit src ld (verified)
__global__ void k_wt2(const float* __restrict__ src, u16* __restrict__ dst,
                      int K, int N, int lds){
  __shared__ float t[32][33];
  int n0 = blockIdx.x*32, k0 = blockIdx.y*32;
  int tx = threadIdx.x, ty = threadIdx.y;
  #pragma unroll
  for(int i=0;i<32;i+=8){
    int k = k0+ty+i, n = n0+tx;
    t[ty+i][tx] = (n<N) ? src[(size_t)k*lds+n] : 0.f;
  }
  __syncthreads();
  #pragma unroll
  for(int i=0;i<32;i+=8){
    int n = n0+ty+i, k = k0+tx;
    if(n<N) dst[(size_t)n*K+k] = cvt_bf16(t[tx][ty+i]);
  }
}

// batched V-transpose
__global__ void k_vtb(const float* __restrict__ VV, u16* __restrict__ VT){
  __shared__ float t[32][33];
  int z = blockIdx.z, b = z>>2, h = z&3;
  const float* src = VV + (size_t)b*524288 + h*128;
  u16* dst = VT + (size_t)z*131072;
  int n0 = blockIdx.x*32, k0 = blockIdx.y*32;
  int tx = threadIdx.x, ty = threadIdx.y;
  #pragma unroll
  for(int i=0;i<32;i+=8){
    int k = k0+ty+i, n = n0+tx;
    t[ty+i][tx] = src[(size_t)k*512+n];
  }
  __syncthreads();
  #pragma unroll
  for(int i=0;i<32;i+=8){
    int n = n0+ty+i, k = k0+tx;
    dst[(size_t)n*1024+k] = cvt_bf16(t[tx][ty+i]);
  }
}

// XdT via LDS-tiled transpose
__global__ void k_xdtt(const float* __restrict__ XC, const float* __restrict__ DT,
                       u16* __restrict__ XdT){
  __shared__ float t[32][33];
  int z = blockIdx.z;
  int h = z & 15, bc = z >> 4;
  int b = bc >> 3, c = bc & 7;
  int p0 = blockIdx.x*32, s0 = blockIdx.y*32;
  int tx = threadIdx.x, ty = threadIdx.y;
  int gbase = b*SEQL + c*CKS;
  #pragma unroll
  for(int i=0;i<32;i+=8){
    int s = s0+ty+i, p = p0+tx;
    int g = gbase + s;
    t[ty+i][tx] = XC[(size_t)g*CVD + h*HD + p] * DT[(size_t)g*NH + h];
  }
  __syncthreads();
  u16* dst = XdT + (size_t)z*16384;
  #pragma unroll
  for(int i=0;i<32;i+=8){
    int p = p0+ty+i, s = s0+tx;
    dst[(size_t)p*256 + s] = cvt_bf16(t[tx][ty+i]);
  }
}

// batched B-transpose
__global__ void k_btc(const u16* __restrict__ Bbf, u16* __restrict__ BTc){
  __shared__ u16 t[32][33];
  int bc = blockIdx.z;
  const u16* src = Bbf + (size_t)bc*16384;
  u16* dst = BTc + (size_t)bc*16384;
  int n0 = blockIdx.x*32, l0 = blockIdx.y*32;
  int tx = threadIdx.x, ty = threadIdx.y;
  #pragma unroll
  for(int i=0;i<32;i+=8){
    int l = l0+ty+i, n = n0+tx;
    t[ty+i][tx] = src[(size_t)l*64+n];
  }
  __syncthreads();
  #pragma unroll
  for(int i=0;i<32;i+=8){
    int n = n0+ty+i, l = l0+tx;
    dst[(size_t)n*256+l] = t[tx][ty+i];
  }
}

// ---------------- MFMA bf16 GEMM, emap0, global_load_lds staging ----------------
__global__ __launch_bounds__(256) void k_mg(
    const u16* __restrict__ A, const u16* __restrict__ BT,
    float* __restrict__ C, int M, int N, int K, int lda, int ldb, int ldc)
{
  __shared__ u16 As[128*32];
  __shared__ u16 Bs[128*32];
  const int tid = threadIdx.x;
  const int row0 = blockIdx.y*128, col0 = blockIdx.x*128;
  const int lane = tid & 63, wave = tid >> 6;
  const int wm = wave >> 1, wn = wave & 1;
  const int lr = lane & 15, ksg = (lane >> 4);
  const int srow = lane >> 2;
  const int slot = lane & 3;
  f32x4 acc[4][4];
  #pragma unroll
  for(int i=0;i<4;i++)
    #pragma unroll
    for(int j=0;j<4;j++) acc[i][j] = (f32x4){0.f,0.f,0.f,0.f};
  for(int k0=0;k0<K;k0+=32){
    #pragma unroll
    for(int i=0;i<2;i++){
      int seg = wave*2 + i;
      int row = seg*16 + srow;
      int kk  = slot ^ ((row>>1)&3);
      const u16* ga = A + (size_t)(row0+row)*lda + k0 + kk*8;
      __builtin_amdgcn_global_load_lds(
        (const __attribute__((address_space(1))) void*)ga,
        (__attribute__((address_space(3))) void*)&As[seg*512], 16, 0, 0);
      int bcol = col0 + row; if(bcol > N-1) bcol = N-1;
      const u16* gb = BT + (size_t)bcol*ldb + k0 + kk*8;
      __builtin_amdgcn_global_load_lds(
        (const __attribute__((address_space(1))) void*)gb,
        (__attribute__((address_space(3))) void*)&Bs[seg*512], 16, 0, 0);
    }
    __syncthreads();
    bf16x8 afr[4], bfr[4];
    #pragma unroll
    for(int i=0;i<4;i++){
      int ar = wm*64+i*16+lr;
      afr[i] = *reinterpret_cast<const bf16x8*>(&As[ar*32 + (ksg^((ar>>1)&3))*8]);
    }
    #pragma unroll
    for(int j=0;j<4;j++){
      int br = wn*64+j*16+lr;
      bfr[j] = *reinterpret_cast<const bf16x8*>(&Bs[br*32 + (ksg^((br>>1)&3))*8]);
    }
    #pragma unroll
    for(int i=0;i<4;i++)
      #pragma unroll
      for(int j=0;j<4;j++)
        acc[i][j] = __builtin_amdgcn_mfma_f32_16x16x32_bf16(afr[i], bfr[j], acc[i][j], 0, 0, 0);
    __syncthreads();
  }
  const int hi = lane >> 4, lo = lane & 15;
  #pragma unroll
  for(int i=0;i<4;i++)
    #pragma unroll
    for(int j=0;j<4;j++)
      #pragma unroll
      for(int r=0;r<4;r++){
        int row = row0 + wm*64 + i*16 + 4*hi + r;
        int col = col0 + wn*64 + j*16 + lo;
        if(col < N) C[(size_t)row*ldc + col] = acc[i][j][r];
      }
}

// same core, bf16 output (in_proj -> ZBh)
__global__ __launch_bounds__(256) void k_mgc(
    const u16* __restrict__ A, const u16* __restrict__ BT,
    u16* __restrict__ C, int M, int N, int K, int lda, int ldb, int ldc)
{
  __shared__ u16 As[128*32];
  __shared__ u16 Bs[128*32];
  const int tid = threadIdx.x;
  const int row0 = blockIdx.y*128, col0 = blockIdx.x*128;
  const int lane = tid & 63, wave = tid >> 6;
  const int wm = wave >> 1, wn = wave & 1;
  const int lr = lane & 15, ksg = (lane >> 4);
  const int srow = lane >> 2;
  const int slot = lane & 3;
  f32x4 acc[4][4];
  #pragma unroll
  for(int i=0;i<4;i++)
    #pragma unroll
    for(int j=0;j<4;j++) acc[i][j] = (f32x4){0.f,0.f,0.f,0.f};
  for(int k0=0;k0<K;k0+=32){
    #pragma unroll
    for(int i=0;i<2;i++){
      int seg = wave*2 + i;
      int row = seg*16 + srow;
      int kk  = slot ^ ((row>>1)&3);
      const u16* ga = A + (size_t)(row0+row)*lda + k0 + kk*8;
      __builtin_amdgcn_global_load_lds(
        (const __attribute__((address_space(1))) void*)ga,
        (__attribute__((address_space(3))) void*)&As[seg*512], 16, 0, 0);
      int bcol = col0 + row; if(bcol > N-1) bcol = N-1;
      const u16* gb = BT + (size_t)bcol*ldb + k0 + kk*8;
      __builtin_amdgcn_global_load_lds(
        (const __attribute__((address_space(1))) void*)gb,
        (__attribute__((address_space(3))) void*)&Bs[seg*512], 16, 0, 0);
    }
    __syncthreads();
    bf16x8 afr[4], bfr[4];
    #pragma unroll
    for(int i=0;i<4;i++){
      int ar = wm*64+i*16+lr;
      afr[i] = *reinterpret_cast<const bf16x8*>(&As[ar*32 + (ksg^((ar>>1)&3))*8]);
    }
    #pragma unroll
    for(int j=0;j<4;j++){
      int br = wn*64+j*16+lr;
      bfr[j] = *reinterpret_cast<const bf16x8*>(&Bs[br*32 + (ksg^((br>>1)&3))*8]);
    }
    #pragma unroll
    for(int i=0;i<4;i++)
      #pragma unroll
      for(int j=0;j<4;j++)
        acc[i][j] = __builtin_amdgcn_mfma_f32_16x16x32_bf16(afr[i], bfr[j], acc[i][j], 0, 0, 0);
    __syncthreads();
  }
  const int hi = lane >> 4, lo = lane & 15;
  #pragma unroll
  for(int i=0;i<4;i++)
    #pragma unroll
    for(int j=0;j<4;j++)
      #pragma unroll
      for(int r=0;r<4;r++){
        int row = row0 + wm*64 + i*16 + 4*hi + r;
        int col = col0 + wn*64 + j*16 + lo;
        if(col < N) C[(size_t)row*ldc + col] = cvt_bf16(acc[i][j][r]);
      }
}

// out_proj GEMM, gload_lds staging + fused flip-add epilogue
__global__ __launch_bounds__(256) void k_mgo(
    const u16* __restrict__ A, const u16* __restrict__ BT,
    float* __restrict__ H, int flip)
{
  const int N = 512, K = 1024;
  __shared__ u16 As[128*32];
  __shared__ u16 Bs[128*32];
  const int tid = threadIdx.x;
  const int row0 = blockIdx.y*128, col0 = blockIdx.x*128;
  const int lane = tid & 63, wave = tid >> 6;
  const int wm = wave >> 1, wn = wave & 1;
  const int lr = lane & 15, ksg = (lane >> 4);
  const int srow = lane >> 2;
  const int slot = lane & 3;
  f32x4 acc[4][4];
  #pragma unroll
  for(int i=0;i<4;i++)
    #pragma unroll
    for(int j=0;j<4;j++) acc[i][j] = (f32x4){0.f,0.f,0.f,0.f};
  for(int k0=0;k0<K;k0+=32){
    #pragma unroll
    for(int i=0;i<2;i++){
      int seg = wave*2 + i;
      int row = seg*16 + srow;
      int kk  = slot ^ ((row>>1)&3);
      const u16* ga = A + (size_t)(row0+row)*K + k0 + kk*8;
      __builtin_amdgcn_global_load_lds(
        (const __attribute__((address_space(1))) void*)ga,
        (__attribute__((address_space(3))) void*)&As[seg*512], 16, 0, 0);
      int bcol = col0 + row; if(bcol > N-1) bcol = N-1;
      const u16* gb = BT + (size_t)bcol*K + k0 + kk*8;
      __builtin_amdgcn_global_load_lds(
        (const __attribute__((address_space(1))) void*)gb,
        (__attribute__((address_space(3))) void*)&Bs[seg*512], 16, 0, 0);
    }
    __syncthreads();
    bf16x8 afr[4], bfr[4];
    #pragma unroll
    for(int i=0;i<4;i++){
      int ar = wm*64+i*16+lr;
      afr[i] = *reinterpret_cast<const bf16x8*>(&As[ar*32 + (ksg^((ar>>1)&3))*8]);
    }
    #pragma unroll
    for(int j=0;j<4;j++){
      int br = wn*64+j*16+lr;
      bfr[j] = *reinterpret_cast<const bf16x8*>(&Bs[br*32 + (ksg^((br>>1)&3))*8]);
    }
    #pragma unroll
    for(int i=0;i<4;i++)
      #pragma unroll
      for(int j=0;j<4;j++)
        acc[i][j] = __builtin_amdgcn_mfma_f32_16x16x32_bf16(afr[i], bfr[j], acc[i][j], 0, 0, 0);
    __syncthreads();
  }
  const int hi = lane >> 4, lo = lane & 15;
  #pragma unroll
  for(int i=0;i<4;i++)
    #pragma unroll
    for(int j=0;j<4;j++)
      #pragma unroll
      for(int r=0;r<4;r++){
        int row = row0 + wm*64 + i*16 + 4*hi + r;
        int col = col0 + wn*64 + j*16 + lo;
        if(col < N){
          int b = row >> 11, l = row & (SEQL-1);
          int sl = flip ? (SEQL-1-l) : l;
          size_t ci = (size_t)(b*SEQL + sl)*DM + col;
          H[ci] += acc[i][j][r];
        }
      }
}

// batched variant: verified core + z-strided base offsets only
__global__ __launch_bounds__(256) void k_mgb(
    const u16* __restrict__ A0, const u16* __restrict__ BT0,
    float* __restrict__ C0, int M, int N, int K, int lda, int ldb, int ldc,
    long sAz, long sBz, long sCo, long sCi, int shC)
{
  const int z = blockIdx.z;
  const u16* A  = A0  + (size_t)z*sAz;
  const u16* BT = BT0 + (size_t)z*sBz;
  float* C = C0 + (size_t)(z>>shC)*sCo + (size_t)(z & ((1<<shC)-1))*sCi;
  __shared__ uint4 As4[128*5];
  __shared__ uint4 Bs4[128*5];
  const int tid = threadIdx.x;
  const int row0 = blockIdx.y*128, col0 = blockIdx.x*128;
  const int lane = tid & 63, wave = tid >> 6;
  const int wm = wave >> 1, wn = wave & 1;
  const int lr = lane & 15, ksg = (lane >> 4);
  f32x4 acc[4][4];
  #pragma unroll
  for(int i=0;i<4;i++)
    #pragma unroll
    for(int j=0;j<4;j++) acc[i][j] = (f32x4){0.f,0.f,0.f,0.f};
  for(int k0=0;k0<K;k0+=32){
    #pragma unroll
    for(int i=0;i<2;i++){
      int t2 = tid + i*256;
      int rr = t2 >> 2, sg = (t2 & 3);
      uint4 av = *reinterpret_cast<const uint4*>(A + (size_t)(row0+rr)*lda + k0 + sg*8);
      uint4 bv = {0u,0u,0u,0u};
      if(col0+rr < N) bv = *reinterpret_cast<const uint4*>(BT + (size_t)(col0+rr)*ldb + k0 + sg*8);
      As4[rr*5 + sg] = av;
      Bs4[rr*5 + sg] = bv;
    }
    __syncthreads();
    bf16x8 afr[4], bfr[4];
    #pragma unroll
    for(int i=0;i<4;i++) afr[i] = *reinterpret_cast<const bf16x8*>(&As4[(wm*64+i*16+lr)*5 + ksg]);
    #pragma unroll
    for(int j=0;j<4;j++) bfr[j] = *reinterpret_cast<const bf16x8*>(&Bs4[(wn*64+j*16+lr)*5 + ksg]);
    #pragma unroll
    for(int i=0;i<4;i++)
      #pragma unroll
      for(int j=0;j<4;j++)
        acc[i][j] = __builtin_amdgcn_mfma_f32_16x16x32_bf16(afr[i], bfr[j], acc[i][j], 0, 0, 0);
    __syncthreads();
  }
  const int hi = lane >> 4, lo = lane & 15;
  #pragma unroll
  for(int i=0;i<4;i++)
    #pragma unroll
    for(int j=0;j<4;j++)
      #pragma unroll
      for(int r=0;r<4;r++){
        int row = row0 + wm*64 + i*16 + 4*hi + r;
        int col = col0 + wn*64 + j*16 + lo;
        if(col < N) C[(size_t)row*ldc + col] = acc[i][j][r];
      }
}

// FUSED Y_diag + Y_off + gate (ZBh bf16; static causal skip via uniform branch)
__global__ __launch_bounds__(256) void k_mgf(
    const float* __restrict__ Sf, const float* __restrict__ ACUM,
    const u16* __restrict__ XdT, const u16* __restrict__ Cb0,
    const u16* __restrict__ PV0, const float* __restrict__ XCp,
    const u16* __restrict__ ZBh, const float* __restrict__ Dp,
    float* __restrict__ Y)
{
  const int z = blockIdx.z;
  const int h = z & 15, bc = z >> 4;
  const int b = bc >> 3, c = bc & 7;
  const float* Az = Sf + (size_t)bc*65536;
  const float* Acp = ACUM + (size_t)z*256;
  const u16* BT1 = XdT + (size_t)z*16384;
  const u16* A2  = Cb0 + (size_t)bc*16384;
  const u16* BT2 = PV0 + (size_t)bc*65536 + (size_t)h*4096;
  __shared__ uint4 As4[128*5];
  __shared__ uint4 Bs4[128*5];
  __shared__ float AcS[256];
  const int tid = threadIdx.x;
  AcS[tid] = Acp[tid];
  __syncthreads();
  const int row0 = blockIdx.y*128;
  const int lane = tid & 63, wave = tid >> 6;
  const int wm = wave >> 1, wn = wave & 1;
  const int lr = lane & 15, ksg = (lane >> 4);
  f32x4 acc[4][4];
  #pragma unroll
  for(int i=0;i<4;i++)
    #pragma unroll
    for(int j=0;j<4;j++) acc[i][j] = (f32x4){0.f,0.f,0.f,0.f};
  // part-1 tile body (G-formation staging + MFMA), shared by both unrolled paths
  auto p1tile = [&](int k0) __attribute__((always_inline)) {
    #pragma unroll
    for(int i=0;i<2;i++){
      int t2 = tid + i*256;
      int rr = t2 >> 2, sg = (t2 & 3);
      int l = row0 + rr;
      int sbase = k0 + sg*8;
      float4 v0 = *reinterpret_cast<const float4*>(Az + (size_t)l*256 + sbase);
      float4 v1 = *reinterpret_cast<const float4*>(Az + (size_t)l*256 + sbase + 4);
      float acl = AcS[l];
      float vv[8] = {v0.x,v0.y,v0.z,v0.w,v1.x,v1.y,v1.z,v1.w};
      u16 gbuf[8];
      #pragma unroll
      for(int e=0;e<8;e++){
        int s = sbase + e;
        float g = 0.f;
        if(s <= l) g = __expf(acl - AcS[s]) * vv[e];
        gbuf[e] = cvt_bf16(g);
      }
      As4[rr*5 + sg] = *reinterpret_cast<uint4*>(gbuf);
      uint4 bv = {0u,0u,0u,0u};
      if(rr < 64) bv = *reinterpret_cast<const uint4*>(BT1 + (size_t)rr*256 + sbase);
      Bs4[rr*5 + sg] = bv;
    }
    __syncthreads();
    bf16x8 afr[4], bfr[4];
    #pragma unroll
    for(int i=0;i<4;i++) afr[i] = *reinterpret_cast<const bf16x8*>(&As4[(wm*64+i*16+lr)*5 + ksg]);
    #pragma unroll
    for(int j=0;j<4;j++) bfr[j] = *reinterpret_cast<const bf16x8*>(&Bs4[(wn*64+j*16+lr)*5 + ksg]);
    #pragma unroll
    for(int i=0;i<4;i++)
      #pragma unroll
      for(int j=0;j<4;j++)
        acc[i][j] = __builtin_amdgcn_mfma_f32_16x16x32_bf16(afr[i], bfr[j], acc[i][j], 0, 0, 0);
    __syncthreads();
  };
  // block-uniform branch; both loops have static trip counts (full unroll).
  // lower half (rows 0..127): tiles k0>=128 are all-zero (s>l) -> skipped, bit-exact.
  if(row0 == 0){
    #pragma unroll
    for(int t=0;t<4;t++) p1tile(t*32);
  } else {
    #pragma unroll
    for(int t=0;t<8;t++) p1tile(t*32);
  }
  // ---- part 2: Y_off (K=64), C rows pre-scaled by exp(Ac[row]) ----
  for(int k0=0;k0<64;k0+=32){
    #pragma unroll
    for(int i=0;i<2;i++){
      int t2 = tid + i*256;
      int rr = t2 >> 2, sg = (t2 & 3);
      int sbase = k0 + sg*8;
      uint4 raw = *reinterpret_cast<const uint4*>(A2 + (size_t)(row0+rr)*64 + sbase);
      const u16* rp = reinterpret_cast<const u16*>(&raw);
      float scale = __expf(AcS[row0+rr]);
      u16 buf[8];
      #pragma unroll
      for(int e=0;e<8;e++) buf[e] = cvt_bf16(bf2f(rp[e]) * scale);
      As4[rr*5 + sg] = *reinterpret_cast<uint4*>(buf);
      uint4 bv = {0u,0u,0u,0u};
      if(rr < 64) bv = *reinterpret_cast<const uint4*>(BT2 + (size_t)rr*64 + sbase);
      Bs4[rr*5 + sg] = bv;
    }
    __syncthreads();
    bf16x8 afr[4], bfr[4];
    #pragma unroll
    for(int i=0;i<4;i++) afr[i] = *reinterpret_cast<const bf16x8*>(&As4[(wm*64+i*16+lr)*5 + ksg]);
    #pragma unroll
    for(int j=0;j<4;j++) bfr[j] = *reinterpret_cast<const bf16x8*>(&Bs4[(wn*64+j*16+lr)*5 + ksg]);
    #pragma unroll
    for(int i=0;i<4;i++)
      #pragma unroll
      for(int j=0;j<4;j++)
        acc[i][j] = __builtin_amdgcn_mfma_f32_16x16x32_bf16(afr[i], bfr[j], acc[i][j], 0, 0, 0);
    __syncthreads();
  }
  // ---- epilogue: gate + write-only Y ----
  const int hi = lane >> 4, lo = lane & 15;
  #pragma unroll
  for(int i=0;i<4;i++)
    #pragma unroll
    for(int j=0;j<4;j++)
      #pragma unroll
      for(int r=0;r<4;r++){
        int row = row0 + wm*64 + i*16 + 4*hi + r;
        int col = wn*64 + j*16 + lo;
        if(col < 64){
          int g = b*SEQL + c*CKS + row;
          int ch = h*HD + col;
          float xh = XCp[(size_t)g*CVD + ch];
          float zg = bf2f(ZBh[(size_t)g*DIP + ch]);
          float v = acc[i][j][r] + Dp[h]*xh;
          float sig = 1.f/(1.f+expf(-zg));
          Y[(size_t)g*DIN + ch] = v * (zg*sig);
        }
      }
}

// states via MFMA
__global__ __launch_bounds__(256) void k_mgs(
    const u16* __restrict__ XdT, const u16* __restrict__ BTc,
    const float* __restrict__ ACUM, float* __restrict__ ST)
{
  const int z = blockIdx.z;
  const int bc = z >> 4;
  const u16* Ap = XdT + (size_t)z*16384;
  const u16* BT = BTc + (size_t)bc*16384;
  float* Cp = ST + (size_t)z*4096;
  __shared__ uint4 As4[128*5];
  __shared__ uint4 Bs4[128*5];
  __shared__ float decS[256];
  const int tid = threadIdx.x;
  {
    const float* Acp = ACUM + (size_t)z*256;
    decS[tid] = __expf(Acp[255] - Acp[tid]);
  }
  __syncthreads();
  const int lane = tid & 63, wave = tid >> 6;
  const int wm = wave >> 1, wn = wave & 1;
  const int lr = lane & 15, ksg = (lane >> 4);
  f32x4 acc[4][4];
  #pragma unroll
  for(int i=0;i<4;i++)
    #pragma unroll
    for(int j=0;j<4;j++) acc[i][j] = (f32x4){0.f,0.f,0.f,0.f};
  for(int k0=0;k0<256;k0+=32){
    #pragma unroll
    for(int i=0;i<2;i++){
      int t2 = tid + i*256;
      int rr = t2 >> 2, sg = (t2 & 3);
      int sbase = k0 + sg*8;
      uint4 av = {0u,0u,0u,0u};
      if(rr < 64){
        uint4 raw = *reinterpret_cast<const uint4*>(Ap + (size_t)rr*256 + sbase);
        const u16* rp = reinterpret_cast<const u16*>(&raw);
        u16 buf[8];
        #pragma unroll
        for(int e=0;e<8;e++) buf[e] = cvt_bf16(bf2f(rp[e]) * decS[sbase+e]);
        av = *reinterpret_cast<uint4*>(buf);
      }
      As4[rr*5 + sg] = av;
      uint4 bv = {0u,0u,0u,0u};
      if(rr < 64) bv = *reinterpret_cast<const uint4*>(BT + (size_t)rr*256 + sbase);
      Bs4[rr*5 + sg] = bv;
    }
    __syncthreads();
    bf16x8 afr[4], bfr[4];
    #pragma unroll
    for(int i=0;i<4;i++) afr[i] = *reinterpret_cast<const bf16x8*>(&As4[(wm*64+i*16+lr)*5 + ksg]);
    #pragma unroll
    for(int j=0;j<4;j++) bfr[j] = *reinterpret_cast<const bf16x8*>(&Bs4[(wn*64+j*16+lr)*5 + ksg]);
    #pragma unroll
    for(int i=0;i<4;i++)
      #pragma unroll
      for(int j=0;j<4;j++)
        acc[i][j] = __builtin_amdgcn_mfma_f32_16x16x32_bf16(afr[i], bfr[j], acc[i][j], 0, 0, 0);
    __syncthreads();
  }
  const int hi = lane >> 4, lo = lane & 15;
  #pragma unroll
  for(int i=0;i<4;i++)
    #pragma unroll
    for(int j=0;j<4;j++)
      #pragma unroll
      for(int r=0;r<4;r++){
        int row = wm*64 + i*16 + 4*hi + r;
        int col = wn*64 + j*16 + lo;
        if(row < 64 && col < 64) Cp[(size_t)row*64 + col] = acc[i][j][r];
      }
}

// batched attention GEMM
__global__ __launch_bounds__(256) void k_mgab(
    const u16* __restrict__ A0, const u16* __restrict__ BT0,
    float* __restrict__ C0, u16* __restrict__ Cb0,
    int M, int N, int K, int lda, int ldb, int ldc,
    long sAo, long sAi, long sBo, long sBi, long sCo, long sCi, float scale)
{
  const int z = blockIdx.z;
  const u16* A  = A0  + (size_t)(z>>2)*sAo + (size_t)(z&3)*sAi;
  const u16* BT = BT0 + (size_t)(z>>2)*sBo + (size_t)(z&3)*sBi;
  const size_t offC = (size_t)(z>>2)*sCo + (size_t)(z&3)*sCi;
  __shared__ uint4 As4[128*5];
  __shared__ uint4 Bs4[128*5];
  const int tid = threadIdx.x;
  const int row0 = blockIdx.y*128, col0 = blockIdx.x*128;
  const int lane = tid & 63, wave = tid >> 6;
  const int wm = wave >> 1, wn = wave & 1;
  const int lr = lane & 15, ksg = (lane >> 4);
  f32x4 acc[4][4];
  #pragma unroll
  for(int i=0;i<4;i++)
    #pragma unroll
    for(int j=0;j<4;j++) acc[i][j] = (f32x4){0.f,0.f,0.f,0.f};
  for(int k0=0;k0<K;k0+=32){
    #pragma unroll
    for(int i=0;i<2;i++){
      int t2 = tid + i*256;
      int rr = t2 >> 2, sg = (t2 & 3);
      uint4 av = *reinterpret_cast<const uint4*>(A + (size_t)(row0+rr)*lda + k0 + sg*8);
      uint4 bv = {0u,0u,0u,0u};
      if(col0+rr < N) bv = *reinterpret_cast<const uint4*>(BT + (size_t)(col0+rr)*ldb + k0 + sg*8);
      As4[rr*5 + sg] = av;
      Bs4[rr*5 + sg] = bv;
    }
    __syncthreads();
    bf16x8 afr[4], bfr[4];
    #pragma unroll
    for(int i=0;i<4;i++) afr[i] = *reinterpret_cast<const bf16x8*>(&As4[(wm*64+i*16+lr)*5 + ksg]);
    #pragma unroll
    for(int j=0;j<4;j++) bfr[j] = *reinterpret_cast<const bf16x8*>(&Bs4[(wn*64+j*16+lr)*5 + ksg]);
    #pragma unroll
    for(int i=0;i<4;i++)
      #pragma unroll
      for(int j=0;j<4;j++)
        acc[i][j] = __builtin_amdgcn_mfma_f32_16x16x32_bf16(afr[i], bfr[j], acc[i][j], 0, 0, 0);
    __syncthreads();
  }
  const int hi = lane >> 4, lo = lane & 15;
  #pragma unroll
  for(int i=0;i<4;i++)
    #pragma unroll
    for(int j=0;j<4;j++)
      #pragma unroll
      for(int r=0;r<4;r++){
        int row = row0 + wm*64 + i*16 + 4*hi + r;
        int col = col0 + wn*64 + j*16 + lo;
        if(col < N){
          float v = acc[i][j][r] * scale;
          size_t ci = offC + (size_t)row*ldc + col;
          if(C0) C0[ci] = v;
          else   Cb0[ci] = cvt_bf16(v);
        }
      }
}

// verified core + arithmetic epilogue (attention projections)
__global__ __launch_bounds__(256) void k_mge(
    const u16* __restrict__ A, const u16* __restrict__ BT,
    const float* __restrict__ bias, const float* __restrict__ res,
    float* __restrict__ C, u16* __restrict__ Cbf,
    int M, int N, int K, int lda, int ldb, int ldc, float scale, int act)
{
  __shared__ uint4 As4[128*5];
  __shared__ uint4 Bs4[128*5];
  const int tid = threadIdx.x;
  const int row0 = blockIdx.y*128, col0 = blockIdx.x*128;
  const int lane = tid & 63, wave = tid >> 6;
  const int wm = wave >> 1, wn = wave & 1;
  const int lr = lane & 15, ksg = (lane >> 4);
  f32x4 acc[4][4];
  #pragma unroll
  for(int i=0;i<4;i++)
    #pragma unroll
    for(int j=0;j<4;j++) acc[i][j] = (f32x4){0.f,0.f,0.f,0.f};
  for(int k0=0;k0<K;k0+=32){
    #pragma unroll
    for(int i=0;i<2;i++){
      int t2 = tid + i*256;
      int rr = t2 >> 2, sg = (t2 & 3);
      uint4 av = *reinterpret_cast<const uint4*>(A + (size_t)(row0+rr)*lda + k0 + sg*8);
      uint4 bv = {0u,0u,0u,0u};
      if(col0+rr < N) bv = *reinterpret_cast<const uint4*>(BT + (size_t)(col0+rr)*ldb + k0 + sg*8);
      As4[rr*5 + sg] = av;
      Bs4[rr*5 + sg] = bv;
    }
    __syncthreads();
    bf16x8 afr[4], bfr[4];
    #pragma unroll
    for(int i=0;i<4;i++) afr[i] = *reinterpret_cast<const bf16x8*>(&As4[(wm*64+i*16+lr)*5 + ksg]);
    #pragma unroll
    for(int j=0;j<4;j++) bfr[j] = *reinterpret_cast<const bf16x8*>(&Bs4[(wn*64+j*16+lr)*5 + ksg]);
    #pragma unroll
    for(int i=0;i<4;i++)
      #pragma unroll
      for(int j=0;j<4;j++)
        acc[i][j] = __builtin_amdgcn_mfma_f32_16x16x32_bf16(afr[i], bfr[j], acc[i][j], 0, 0, 0);
    __syncthreads();
  }
  const int hi = lane >> 4, lo = lane & 15;
  #pragma unroll
  for(int i=0;i<4;i++)
    #pragma unroll
    for(int j=0;j<4;j++)
      #pragma unroll
      for(int r=0;r<4;r++){
        int row = row0 + wm*64 + i*16 + 4*hi + r;
        int col = col0 + wn*64 + j*16 + lo;
        if(col < N){
          float v = acc[i][j][r];
          if(bias) v += bias[col];
          v *= scale;
          if(act==1) v = 0.5f*v*(1.f+erff(v*0.70710678118654752f));
          size_t ci = (size_t)row*ldc + col;
          if(res) v += res[ci];
          if(C) C[ci] = v;
          else  Cbf[ci] = cvt_bf16(v);
        }
      }
}

// in-place row softmax over 1024 bf16
__global__ void k_sm(u16* __restrict__ S){
  size_t row = blockIdx.x;
  u16* p = S + row*1024;
  int tid = threadIdx.x;
  ushort4 u = reinterpret_cast<ushort4*>(p)[tid];
  float v0=bf2f(u.x), v1=bf2f(u.y), v2=bf2f(u.z), v3=bf2f(u.w);
  float m = fmaxf(fmaxf(v0,v1),fmaxf(v2,v3));
  __shared__ float red[256];
  red[tid]=m; __syncthreads();
  for(int o=128;o>0;o>>=1){ if(tid<o) red[tid]=fmaxf(red[tid],red[tid+o]); __syncthreads(); }
  m = red[0]; __syncthreads();
  v0=__expf(v0-m); v1=__expf(v1-m); v2=__expf(v2-m); v3=__expf(v3-m);
  float s = v0+v1+v2+v3;
  red[tid]=s; __syncthreads();
  for(int o=128;o>0;o>>=1){ if(tid<o) red[tid]+=red[tid+o]; __syncthreads(); }
  float inv = 1.f/red[0];
  ushort4 o4; o4.x=cvt_bf16(v0*inv); o4.y=cvt_bf16(v1*inv); o4.z=cvt_bf16(v2*inv); o4.w=cvt_bf16(v3*inv);
  reinterpret_cast<ushort4*>(p)[tid] = o4;
}

// ---------------- mamba pieces (ZBh bf16) ----------------
__global__ void k_conv4(const u16* __restrict__ ZBh, const float* __restrict__ cw,
                        const float* __restrict__ cb, float* __restrict__ XC){
  int i = blockIdx.x*256 + threadIdx.x;
  if(i >= BS*512*CVD) return;
  int cch = i % CVD;
  int lq = (i / CVD) & 511;
  int b = i / (CVD*512);
  int l0 = lq*4;
  float w[7];
  #pragma unroll
  for(int t=0;t<7;t++){
    int sl = l0 - 3 + t;
    w[t] = (sl >= 0) ? bf2f(ZBh[(size_t)(b*SEQL+sl)*DIP + DIN + cch]) : 0.f;
  }
  float c0 = cw[cch*4+0], c1 = cw[cch*4+1], c2 = cw[cch*4+2], c3 = cw[cch*4+3];
  float bb2 = cb[cch];
  #pragma unroll
  for(int j=0;j<4;j++){
    float v = bb2 + w[j]*c0 + w[j+1]*c1 + w[j+2]*c2 + w[j+3]*c3;
    float sig = 1.f/(1.f+expf(-v));
    XC[(size_t)(b*SEQL + l0 + j)*CVD + cch] = v*sig;
  }
}

__global__ void k_dt(const u16* __restrict__ ZBh, const float* __restrict__ dtb,
                     const float* __restrict__ Alog, float* __restrict__ DT,
                     float* __restrict__ DA){
  int i = blockIdx.x*256 + threadIdx.x;
  if(i >= BS*SEQL*NH) return;
  int h = i & (NH-1);
  int row = i >> 4;
  float raw = bf2f(ZBh[(size_t)row*DIP + (DIN+CVD) + h]) + dtb[h];
  float dt = fmaxf(raw,0.f) + log1pf(expf(-fabsf(raw)));
  DT[i] = dt;
  DA[i] = dt * (-expf(Alog[h]));
}

__global__ void k_acum(const float* __restrict__ DA, float* __restrict__ ACUM,
                       float* __restrict__ CDEC){
  int blk = blockIdx.x;
  int h = blk & 15, c = (blk>>4)&7, b = blk>>7;
  int l = threadIdx.x;
  __shared__ float s[256];
  int gl = c*CKS + l;
  s[l] = DA[(size_t)(b*SEQL + gl)*NH + h];
  __syncthreads();
  for(int off=1; off<256; off<<=1){
    float v = (l>=off) ? s[l-off] : 0.f;
    __syncthreads();
    s[l] += v;
    __syncthreads();
  }
  ACUM[(size_t)blk*CKS + l] = s[l];
  if(l==255) CDEC[blk] = expf(s[255]);
}

// extract B,C as bf16 [8192][64]
__global__ void k_bc(const float* __restrict__ XC, u16* __restrict__ Bbf,
                     u16* __restrict__ Cbf){
  int i = blockIdx.x*256 + threadIdx.x;
  if(i >= NROWS*DST) return;
  int g = i >> 6, n = i & 63;
  Bbf[i] = cvt_bf16(XC[(size_t)g*CVD + DIN + n]);
  Cbf[i] = cvt_bf16(XC[(size_t)g*CVD + DIN + DST + n]);
}

// inter-chunk scan, writing bf16 PREV directly (bit-identical to scan+cvt)
__global__ void k_scan(const float* __restrict__ ST, const float* __restrict__ CDEC,
                       u16* __restrict__ PREVbf){
  int i = blockIdx.x*256 + threadIdx.x;
  if(i >= BS*NH*4096) return;
  int pn = i & 4095;
  int h = (i>>12) & 15;
  int b = i >> 16;
  float run = 0.f;
  for(int c=0;c<8;c++){
    size_t idx = (size_t)((b*8+c)*16+h)*4096 + pn;
    PREVbf[idx] = cvt_bf16(run);
    run = run*CDEC[(b*8+c)*16+h] + ST[idx];
  }
}

// ---------------- attention helpers ----------------
__global__ void k_extract(const float* __restrict__ HF, float* __restrict__ QIN,
                          float* __restrict__ CIN){
  int i = blockIdx.x*256 + threadIdx.x;
  if(i >= BS*1024*DM) return;
  int d = i & (DM-1);
  int q = (i>>9) & 1023;
  int b = i >> 19;
  QIN[i] = HF[(size_t)(b*SEQL + 1024 + q)*DM + d];
  CIN[i] = HF[(size_t)(b*SEQL + q)*DM + d];
}

// ---------------- host ----------------
extern "C" void kernel_launch(void* const* d_in, const int* in_sizes, int n_in,
                              void* d_out, int out_size, void* d_ws, size_t ws_size,
                              hipStream_t stream) {
  (void)in_sizes; (void)n_in; (void)out_size; (void)ws_size;
  const float* x_enc     = (const float*)d_in[0];
  const float* in_proj_w = (const float*)d_in[2];
  const float* conv_w    = (const float*)d_in[3];
  const float* conv_b    = (const float*)d_in[4];
  const float* dt_bias   = (const float*)d_in[5];
  const float* A_log     = (const float*)d_in[6];
  const float* D_param   = (const float*)d_in[7];
  const float* gnorm_w   = (const float*)d_in[8];
  const float* out_proj_w= (const float*)d_in[9];
  const float* norm_w    = (const float*)d_in[10];
  const float* norm_b    = (const float*)d_in[11];
  const float* normf_w   = (const float*)d_in[12];
  const float* normf_b   = (const float*)d_in[13];
  const float* ca_nq_w   = (const float*)d_in[14];
  const float* ca_nq_b   = (const float*)d_in[15];
  const float* ca_nkv_w  = (const float*)d_in[16];
  const float* ca_nkv_b  = (const float*)d_in[17];
  const float* ca_qw     = (const float*)d_in[18];
  const float* ca_kw     = (const float*)d_in[19];
  const float* ca_vw     = (const float*)d_in[20];
  const float* ca_ow     = (const float*)d_in[21];
  const float* ca_qb     = (const float*)d_in[22];
  const float* ca_kb     = (const float*)d_in[23];
  const float* ca_vb     = (const float*)d_in[24];
  const float* ca_ob     = (const float*)d_in[25];
  const float* qp_w      = (const float*)d_in[26];
  const float* qp_b      = (const float*)d_in[27];
  const float* cp_w      = (const float*)d_in[28];
  const float* cp_b      = (const float*)d_in[29];
  const float* dec1_w    = (const float*)d_in[30];
  const float* dec1_b    = (const float*)d_in[31];
  const float* dec2_w    = (const float*)d_in[32];
  const float* dec2_b    = (const float*)d_in[33];

  float* W = (float*)d_ws;
  size_t off = 0;
  auto alloc = [&](size_t n){ float* pp = W + off; off += n; return pp; };
  float* RES  = alloc((size_t)NTOK);
  float* H    = alloc((size_t)NTOK);
  float* HN   = alloc((size_t)NTOK);
  float* HNF  = alloc((size_t)NTOK);
  float* ZB   = alloc((size_t)NROWS*DIP);        // region reused: ZBh bf16 uses half
  float* XC   = alloc((size_t)NROWS*CVD);
  float* DT   = alloc((size_t)NROWS*NH);
  float* DA   = alloc((size_t)NROWS*NH);
  float* ACUM = alloc((size_t)BS*NC*NH*CKS);
  float* CDEC = alloc((size_t)BS*NC*NH);
  float* Y    = alloc((size_t)NROWS*DIN);
  float* ST   = alloc((size_t)BS*NC*NH*4096);
  float* PREV = alloc((size_t)BS*NC*NH*4096);
  float* HF2  = alloc((size_t)NTOK);
  float* HF   = alloc((size_t)NTOK);
  (void)PREV;
  float* YD   = HF2;

  u16* ZBh    = (u16*)ZB;                        // bf16 in_proj output [8192][2192]
  // mamba staging aliases (proven lifetimes):
  u16* Ubf    = (u16*)HF;
  u16* WinTc  = (u16*)(HF + 2097152);
  u16* WoutTc = (u16*)(HF + 2097152 + 561152);
  u16* Ybf    = (u16*)HNF;
  // SSD staging (disjoint within HNF):
  u16*   Bbf    = (u16*)HNF;
  u16*   Cbf    = Bbf + 524288;
  float* Sf     = HNF + 524288;
  u16*   BTc    = (u16*)(HNF + 2621440);
  u16*   PREVbf = (u16*)(HNF + 2883584);
  u16*   XdTg   = (u16*)YD;

  const int TPB = 256;
  const int gTok = (NTOK+TPB-1)/TPB;
  dim3 tb(32,8);

  hipMemcpyAsync(RES, x_enc, (size_t)NTOK*4, hipMemcpyDeviceToDevice, stream);

  for(int layer=0; layer<2; ++layer){
    if(layer>0) k_add_flip<<<gTok,TPB,0,stream>>>(RES, H, 0);
    k_ln<<<NROWS,TPB,0,stream>>>(RES, norm_w + layer*DM, norm_b + layer*DM, HN);
    hipMemsetAsync(H, 0, (size_t)NTOK*4, stream);
    for(int dir=0; dir<2; ++dir){
      int idx = layer*2 + dir;
      const float* cw   = conv_w   + (size_t)idx*CVD*4;
      const float* cb   = conv_b   + (size_t)idx*CVD;
      const float* dtb  = dt_bias  + (size_t)idx*NH;
      const float* Alog = A_log    + (size_t)idx*NH;
      const float* Dp   = D_param  + (size_t)idx*NH;
      const float* gw   = gnorm_w  + (size_t)idx*DIN;

      if(dir==0){
        k_cvt<<<(NTOK/4+TPB-1)/TPB,TPB,0,stream>>>(HN, Ubf, NTOK/4);
      }else{
        k_flip<<<gTok,TPB,0,stream>>>(HNF, HN);
        k_cvt<<<(NTOK/4+TPB-1)/TPB,TPB,0,stream>>>(HNF, Ubf, NTOK/4);
      }
      k_wt2<<<dim3(69,16),tb,0,stream>>>(in_proj_w + (size_t)idx*DM*DIP, WinTc, 512, 2192, 2192);
      k_mgc<<<dim3(18,64),256,0,stream>>>(Ubf, WinTc, ZBh, 8192, 2192, 512, 512, 512, 2192);

      k_conv4<<<(BS*512*CVD+TPB-1)/TPB,TPB,0,stream>>>(ZBh, cw, cb, XC);
      k_dt<<<(BS*SEQL*NH+TPB-1)/TPB,TPB,0,stream>>>(ZBh, dtb, Alog, DT, DA);
      k_acum<<<BS*NC*NH,256,0,stream>>>(DA, ACUM, CDEC);

      // ---- SSD pre-computation ----
      k_bc<<<(NROWS*DST+TPB-1)/TPB,TPB,0,stream>>>(XC, Bbf, Cbf);
      k_mgb<<<dim3(2,2,32),256,0,stream>>>(Cbf, Bbf, Sf,
            256, 256, 64, 64, 64, 256, 16384, 16384, 65536, 0, 0);
      k_xdtt<<<dim3(2,8,512),tb,0,stream>>>(XC, DT, XdTg);
      k_btc<<<dim3(2,8,32),tb,0,stream>>>(Bbf, BTc);
      k_mgs<<<dim3(1,1,512),256,0,stream>>>(XdTg, BTc, ACUM, ST);
      k_scan<<<(BS*NH*4096+TPB-1)/TPB,TPB,0,stream>>>(ST, CDEC, PREVbf);
      // ---- fused Y_diag + Y_off + gate (write-only Y) ----
      k_mgf<<<dim3(1,2,512),256,0,stream>>>(Sf, ACUM, XdTg, Cbf, PREVbf, XC, ZBh, Dp, Y);

      // ---- RMSNorm -> bf16 directly ----
      k_rmsb<<<NROWS,256,0,stream>>>(Y, gw, Ybf);
      k_wt2<<<dim3(16,32),tb,0,stream>>>(out_proj_w + (size_t)idx*DIN*DM, WoutTc, 1024, 512, 512);
      // ---- out_proj with fused flip-add into H ----
      k_mgo<<<dim3(4,64),256,0,stream>>>(Ybf, WoutTc, H, dir);
    }
  }
  k_add_flip<<<gTok,TPB,0,stream>>>(RES, H, 0);
  k_ln<<<NROWS,TPB,0,stream>>>(RES, normf_w, normf_b, HF);

  // ================= attention head — MFMA (batched) =================
  float* P0   = ZB;
  float* QIN  = P0 + 0;
  float* CIN  = P0 + 2097152;
  float* QPb  = P0 + 4194304;
  float* CPb  = P0 + 6291456;
  float* QN   = P0 + 8388608;
  float* CN   = P0 + 10485760;
  float* AO   = P0 + 12582912;
  float* O1   = P0 + 14680064;
  float* D1   = P0 + 16777216;
  float* VV   = D1;
  u16* U0     = (u16*)(P0 + 20971520);
  u16* Qbf    = U0 + 0;
  u16* Cbf2   = U0 + 2097152;
  u16* QNbf   = U0 + 4194304;
  u16* CNbf   = U0 + 6291456;
  u16* QQbf   = U0 + 8388608;
  u16* KKbf   = U0 + 10485760;
  u16* VTbf   = U0 + 12582912;
  u16* AObf   = U0 + 14680064;
  u16* O1bf   = U0 + 16777216;
  u16* qpT    = U0 + 18874368;
  u16* cpT    = qpT + 262144;
  u16* qwT    = qpT + 524288;
  u16* kwT    = qpT + 786432;
  u16* vwT    = qpT + 1048576;
  u16* owT    = qpT + 1310720;
  u16* dec1T  = qpT + 1572864;
  u16* Pbf    = qpT + 2097152;

  const int M2 = BS*1024;
  k_extract<<<(BS*1024*DM+TPB-1)/TPB,TPB,0,stream>>>(HF, QIN, CIN);
  k_cvt<<<(2097152/4+TPB-1)/TPB,TPB,0,stream>>>(QIN, Qbf, 2097152/4);
  k_cvt<<<(2097152/4+TPB-1)/TPB,TPB,0,stream>>>(CIN, Cbf2, 2097152/4);
  k_wt2<<<dim3(16,16),tb,0,stream>>>(qp_w, qpT, 512, 512, 512);
  k_wt2<<<dim3(16,16),tb,0,stream>>>(cp_w, cpT, 512, 512, 512);
  k_wt2<<<dim3(16,16),tb,0,stream>>>(ca_qw, qwT, 512, 512, 512);
  k_wt2<<<dim3(16,16),tb,0,stream>>>(ca_kw, kwT, 512, 512, 512);
  k_wt2<<<dim3(16,16),tb,0,stream>>>(ca_vw, vwT, 512, 512, 512);
  k_wt2<<<dim3(16,16),tb,0,stream>>>(ca_ow, owT, 512, 512, 512);
  k_wt2<<<dim3(32,16),tb,0,stream>>>(dec1_w, dec1T, 512, 1024, 1024);

  k_mge<<<dim3(4,32),256,0,stream>>>(Qbf, qpT, qp_b, nullptr, QPb, nullptr,
                                     M2, 512, 512, 512, 512, 512, 1.f, 0);
  k_mge<<<dim3(4,32),256,0,stream>>>(Cbf2, cpT, cp_b, nullptr, CPb, nullptr,
                                     M2, 512, 512, 512, 512, 512, 1.f, 0);
  k_ln<<<M2,TPB,0,stream>>>(QPb, ca_nq_w, ca_nq_b, QN);
  k_ln<<<M2,TPB,0,stream>>>(CPb, ca_nkv_w, ca_nkv_b, CN);
  k_cvt<<<(2097152/4+TPB-1)/TPB,TPB,0,stream>>>(QN, QNbf, 2097152/4);
  k_cvt<<<(2097152/4+TPB-1)/TPB,TPB,0,stream>>>(CN, CNbf, 2097152/4);
  k_mge<<<dim3(4,32),256,0,stream>>>(QNbf, qwT, ca_qb, nullptr, nullptr, QQbf,
                                     M2, 512, 512, 512, 512, 512, 1.f, 0);
  k_mge<<<dim3(4,32),256,0,stream>>>(CNbf, kwT, ca_kb, nullptr, nullptr, KKbf,
                                     M2, 512, 512, 512, 512, 512, 1.f, 0);
  k_mge<<<dim3(4,32),256,0,stream>>>(CNbf, vwT, ca_vb, nullptr, VV, nullptr,
                                     M2, 512, 512, 512, 512, 512, 1.f, 0);
  k_vtb<<<dim3(4,32,16),tb,0,stream>>>(VV, VTbf);
  const float scl = 0.088388347648318447f;
  k_mgab<<<dim3(8,8,16),256,0,stream>>>(QQbf, KKbf, nullptr, Pbf,
        1024, 1024, 128, 512, 512, 1024,
        524288, 128, 524288, 128, 4194304, 1048576, scl);
  k_sm<<<16384,256,0,stream>>>(Pbf);
  k_mgab<<<dim3(1,8,16),256,0,stream>>>(Pbf, VTbf, AO, nullptr,
        1024, 128, 1024, 1024, 1024, 512,
        4194304, 1048576, 524288, 131072, 524288, 128, 1.f);
  k_cvt<<<(2097152/4+TPB-1)/TPB,TPB,0,stream>>>(AO, AObf, 2097152/4);
  k_mge<<<dim3(4,32),256,0,stream>>>(AObf, owT, ca_ob, QPb, O1, nullptr,
                                     M2, 512, 512, 512, 512, 512, 1.f, 0);
  k_cvt<<<(2097152/4+TPB-1)/TPB,TPB,0,stream>>>(O1, O1bf, 2097152/4);
  k_mge<<<dim3(8,32),256,0,stream>>>(O1bf, dec1T, dec1_b, nullptr, D1, nullptr,
                                     M2, 1024, 512, 512, 512, 1024, 1.f, 1);
  k_dec2<<<M2,256,0,stream>>>(D1, dec2_w, dec2_b, (float*)d_out);
}

// Round 24
// 1267.947 us; speedup vs baseline: 1.0142x; 1.0142x over previous
//
#include <hip/hip_runtime.h>
#include <hip/hip_bf16.h>

#define BS 4
#define SEQL 2048
#define DM 512
#define DIN 1024
#define NH 16
#define HD 64
#define DST 64
#define NC 8
#define CKS 256
#define DIP 2192
#define CVD 1152
#define NROWS (BS*SEQL)          /* 8192 */
#define NTOK (BS*SEQL*DM)        /* 4194304 */

typedef unsigned short u16;
typedef __bf16 bf16x8 __attribute__((ext_vector_type(8)));
typedef float f32x4 __attribute__((ext_vector_type(4)));

__device__ __forceinline__ u16 cvt_bf16(float f){
  unsigned int x = __float_as_uint(f);
  unsigned int r = x + 0x7fffu + ((x>>16)&1u);
  return (u16)(r>>16);
}
// native RNE cast (compiler emits v_cvt_pk_bf16_f32 for adjacent pairs)
__device__ __forceinline__ u16 cvtb(float f){
  union { __bf16 b; u16 u; } cv; cv.b = (__bf16)f; return cv.u;
}
__device__ __forceinline__ float bf2f(u16 u){
  return __uint_as_float(((unsigned int)u)<<16);
}

// ---------------- elementwise (proven) ----------------
__global__ void k_add_flip(float* __restrict__ dst, const float* __restrict__ src, int flip){
  int i = blockIdx.x*256 + threadIdx.x;
  if(i >= NTOK) return;
  int d = i & (DM-1);
  int l = (i >> 9) & (SEQL-1);
  int b = i >> 20;
  int sl = flip ? (SEQL-1-l) : l;
  dst[i] += src[(b*SEQL + sl)*DM + d];
}

__global__ void k_flip(float* __restrict__ dst, const float* __restrict__ src){
  int i = blockIdx.x*256 + threadIdx.x;
  if(i >= NTOK) return;
  int d = i & (DM-1);
  int l = (i >> 9) & (SEQL-1);
  int b = i >> 20;
  dst[i] = src[(b*SEQL + (SEQL-1-l))*DM + d];
}

// f32 -> bf16 (verified round-8)
__global__ void k_cvt(const float* __restrict__ src, u16* __restrict__ dst, int n4){
  int i = blockIdx.x*256 + threadIdx.x;
  if(i >= n4) return;
  float4 f = reinterpret_cast<const float4*>(src)[i];
  ushort4 o; o.x=cvt_bf16(f.x); o.y=cvt_bf16(f.y); o.z=cvt_bf16(f.z); o.w=cvt_bf16(f.w);
  reinterpret_cast<ushort4*>(dst)[i] = o;
}

__global__ void k_ln(const float* __restrict__ X, const float* __restrict__ w,
                     const float* __restrict__ bb, float* __restrict__ O){
  int row = blockIdx.x, tid = threadIdx.x;
  const float* x = X + (size_t)row*DM;
  float* o = O + (size_t)row*DM;
  float s=0.f, s2=0.f;
  for(int j=tid;j<DM;j+=256){ float v=x[j]; s+=v; s2+=v*v; }
  __shared__ float r1[256], r2[256];
  r1[tid]=s; r2[tid]=s2; __syncthreads();
  for(int off=128;off>0;off>>=1){
    if(tid<off){ r1[tid]+=r1[tid+off]; r2[tid]+=r2[tid+off]; }
    __syncthreads();
  }
  float m = r1[0]*(1.f/DM);
  float var = r2[0]*(1.f/DM) - m*m;
  float inv = rsqrtf(var + 1e-5f);
  for(int j=tid;j<DM;j+=256) o[j] = (x[j]-m)*inv*w[j] + bb[j];
}

// RMSNorm reading Y f32, writing bf16 only
__global__ void k_rmsb(const float* __restrict__ Y, const float* __restrict__ gw,
                       u16* __restrict__ Obf){
  int row = blockIdx.x, tid = threadIdx.x;
  const float* y = Y + (size_t)row*DIN;
  float ss=0.f;
  for(int j=tid;j<DIN;j+=256){ float v=y[j]; ss+=v*v; }
  __shared__ float red[256];
  red[tid]=ss; __syncthreads();
  for(int off=128;off>0;off>>=1){
    if(tid<off) red[tid]+=red[tid+off];
    __syncthreads();
  }
  float inv = rsqrtf(red[0]*(1.f/DIN) + 1e-5f);
  for(int j=tid;j<DIN;j+=256) Obf[(size_t)row*DIN + j] = cvt_bf16(y[j]*inv*gw[j]);
}

// dec2
__global__ void k_dec2(const float* __restrict__ D1, const float* __restrict__ w,
                       const float* __restrict__ bb, float* __restrict__ out){
  int row = blockIdx.x, tid = threadIdx.x;
  int lane = tid & 63, wave = tid >> 6;
  const float* x = D1 + (size_t)row*1024;
  float acc[10];
  #pragma unroll
  for(int o=0;o<10;o++) acc[o]=0.f;
  for(int j=tid;j<1024;j+=256){
    float v = x[j];
    const float* wr = w + (size_t)j*10;
    #pragma unroll
    for(int o=0;o<10;o++) acc[o] += v*wr[o];
  }
  __shared__ float red[4][10];
  #pragma unroll
  for(int o=0;o<10;o++){
    float v = acc[o];
    #pragma unroll
    for(int s=32;s>0;s>>=1) v += __shfl_down(v, s, 64);
    if(lane==0) red[wave][o] = v;
  }
  __syncthreads();
  if(tid < 10)
    out[(size_t)row*10 + tid] = red[0][tid]+red[1][tid]+red[2][tid]+red[3][tid] + bb[tid];
}

// transpose-convert with explicit src ld (verified)
__global__ void k_wt2(const float* __restrict__ src, u16* __restrict__ dst,
                      int K, int N, int lds){
  __shared__ float t[32][33];
  int n0 = blockIdx.x*32, k0 = blockIdx.y*32;
  int tx = threadIdx.x, ty = threadIdx.y;
  #pragma unroll
  for(int i=0;i<32;i+=8){
    int k = k0+ty+i, n = n0+tx;
    t[ty+i][tx] = (n<N) ? src[(size_t)k*lds+n] : 0.f;
  }
  __syncthreads();
  #pragma unroll
  for(int i=0;i<32;i+=8){
    int n = n0+ty+i, k = k0+tx;
    if(n<N) dst[(size_t)n*K+k] = cvt_bf16(t[tx][ty+i]);
  }
}

// batched V-transpose
__global__ void k_vtb(const float* __restrict__ VV, u16* __restrict__ VT){
  __shared__ float t[32][33];
  int z = blockIdx.z, b = z>>2, h = z&3;
  const float* src = VV + (size_t)b*524288 + h*128;
  u16* dst = VT + (size_t)z*131072;
  int n0 = blockIdx.x*32, k0 = blockIdx.y*32;
  int tx = threadIdx.x, ty = threadIdx.y;
  #pragma unroll
  for(int i=0;i<32;i+=8){
    int k = k0+ty+i, n = n0+tx;
    t[ty+i][tx] = src[(size_t)k*512+n];
  }
  __syncthreads();
  #pragma unroll
  for(int i=0;i<32;i+=8){
    int n = n0+ty+i, k = k0+tx;
    dst[(size_t)n*1024+k] = cvt_bf16(t[tx][ty+i]);
  }
}

// XdT via LDS-tiled transpose
__global__ void k_xdtt(const float* __restrict__ XC, const float* __restrict__ DT,
                       u16* __restrict__ XdT){
  __shared__ float t[32][33];
  int z = blockIdx.z;
  int h = z & 15, bc = z >> 4;
  int b = bc >> 3, c = bc & 7;
  int p0 = blockIdx.x*32, s0 = blockIdx.y*32;
  int tx = threadIdx.x, ty = threadIdx.y;
  int gbase = b*SEQL + c*CKS;
  #pragma unroll
  for(int i=0;i<32;i+=8){
    int s = s0+ty+i, p = p0+tx;
    int g = gbase + s;
    t[ty+i][tx] = XC[(size_t)g*CVD + h*HD + p] * DT[(size_t)g*NH + h];
  }
  __syncthreads();
  u16* dst = XdT + (size_t)z*16384;
  #pragma unroll
  for(int i=0;i<32;i+=8){
    int p = p0+ty+i, s = s0+tx;
    dst[(size_t)p*256 + s] = cvt_bf16(t[tx][ty+i]);
  }
}

// batched B-transpose
__global__ void k_btc(const u16* __restrict__ Bbf, u16* __restrict__ BTc){
  __shared__ u16 t[32][33];
  int bc = blockIdx.z;
  const u16* src = Bbf + (size_t)bc*16384;
  u16* dst = BTc + (size_t)bc*16384;
  int n0 = blockIdx.x*32, l0 = blockIdx.y*32;
  int tx = threadIdx.x, ty = threadIdx.y;
  #pragma unroll
  for(int i=0;i<32;i+=8){
    int l = l0+ty+i, n = n0+tx;
    t[ty+i][tx] = src[(size_t)l*64+n];
  }
  __syncthreads();
  #pragma unroll
  for(int i=0;i<32;i+=8){
    int n = n0+ty+i, l = l0+tx;
    dst[(size_t)n*256+l] = t[tx][ty+i];
  }
}

// ---------------- MFMA bf16 GEMM, emap0, global_load_lds staging ----------------
__global__ __launch_bounds__(256) void k_mg(
    const u16* __restrict__ A, const u16* __restrict__ BT,
    float* __restrict__ C, int M, int N, int K, int lda, int ldb, int ldc)
{
  __shared__ u16 As[128*32];
  __shared__ u16 Bs[128*32];
  const int tid = threadIdx.x;
  const int row0 = blockIdx.y*128, col0 = blockIdx.x*128;
  const int lane = tid & 63, wave = tid >> 6;
  const int wm = wave >> 1, wn = wave & 1;
  const int lr = lane & 15, ksg = (lane >> 4);
  const int srow = lane >> 2;
  const int slot = lane & 3;
  f32x4 acc[4][4];
  #pragma unroll
  for(int i=0;i<4;i++)
    #pragma unroll
    for(int j=0;j<4;j++) acc[i][j] = (f32x4){0.f,0.f,0.f,0.f};
  for(int k0=0;k0<K;k0+=32){
    #pragma unroll
    for(int i=0;i<2;i++){
      int seg = wave*2 + i;
      int row = seg*16 + srow;
      int kk  = slot ^ ((row>>1)&3);
      const u16* ga = A + (size_t)(row0+row)*lda + k0 + kk*8;
      __builtin_amdgcn_global_load_lds(
        (const __attribute__((address_space(1))) void*)ga,
        (__attribute__((address_space(3))) void*)&As[seg*512], 16, 0, 0);
      int bcol = col0 + row; if(bcol > N-1) bcol = N-1;
      const u16* gb = BT + (size_t)bcol*ldb + k0 + kk*8;
      __builtin_amdgcn_global_load_lds(
        (const __attribute__((address_space(1))) void*)gb,
        (__attribute__((address_space(3))) void*)&Bs[seg*512], 16, 0, 0);
    }
    __syncthreads();
    bf16x8 afr[4], bfr[4];
    #pragma unroll
    for(int i=0;i<4;i++){
      int ar = wm*64+i*16+lr;
      afr[i] = *reinterpret_cast<const bf16x8*>(&As[ar*32 + (ksg^((ar>>1)&3))*8]);
    }
    #pragma unroll
    for(int j=0;j<4;j++){
      int br = wn*64+j*16+lr;
      bfr[j] = *reinterpret_cast<const bf16x8*>(&Bs[br*32 + (ksg^((br>>1)&3))*8]);
    }
    #pragma unroll
    for(int i=0;i<4;i++)
      #pragma unroll
      for(int j=0;j<4;j++)
        acc[i][j] = __builtin_amdgcn_mfma_f32_16x16x32_bf16(afr[i], bfr[j], acc[i][j], 0, 0, 0);
    __syncthreads();
  }
  const int hi = lane >> 4, lo = lane & 15;
  #pragma unroll
  for(int i=0;i<4;i++)
    #pragma unroll
    for(int j=0;j<4;j++)
      #pragma unroll
      for(int r=0;r<4;r++){
        int row = row0 + wm*64 + i*16 + 4*hi + r;
        int col = col0 + wn*64 + j*16 + lo;
        if(col < N) C[(size_t)row*ldc + col] = acc[i][j][r];
      }
}

// same core, bf16 output (in_proj -> ZBh)
__global__ __launch_bounds__(256) void k_mgc(
    const u16* __restrict__ A, const u16* __restrict__ BT,
    u16* __restrict__ C, int M, int N, int K, int lda, int ldb, int ldc)
{
  __shared__ u16 As[128*32];
  __shared__ u16 Bs[128*32];
  const int tid = threadIdx.x;
  const int row0 = blockIdx.y*128, col0 = blockIdx.x*128;
  const int lane = tid & 63, wave = tid >> 6;
  const int wm = wave >> 1, wn = wave & 1;
  const int lr = lane & 15, ksg = (lane >> 4);
  const int srow = lane >> 2;
  const int slot = lane & 3;
  f32x4 acc[4][4];
  #pragma unroll
  for(int i=0;i<4;i++)
    #pragma unroll
    for(int j=0;j<4;j++) acc[i][j] = (f32x4){0.f,0.f,0.f,0.f};
  for(int k0=0;k0<K;k0+=32){
    #pragma unroll
    for(int i=0;i<2;i++){
      int seg = wave*2 + i;
      int row = seg*16 + srow;
      int kk  = slot ^ ((row>>1)&3);
      const u16* ga = A + (size_t)(row0+row)*lda + k0 + kk*8;
      __builtin_amdgcn_global_load_lds(
        (const __attribute__((address_space(1))) void*)ga,
        (__attribute__((address_space(3))) void*)&As[seg*512], 16, 0, 0);
      int bcol = col0 + row; if(bcol > N-1) bcol = N-1;
      const u16* gb = BT + (size_t)bcol*ldb + k0 + kk*8;
      __builtin_amdgcn_global_load_lds(
        (const __attribute__((address_space(1))) void*)gb,
        (__attribute__((address_space(3))) void*)&Bs[seg*512], 16, 0, 0);
    }
    __syncthreads();
    bf16x8 afr[4], bfr[4];
    #pragma unroll
    for(int i=0;i<4;i++){
      int ar = wm*64+i*16+lr;
      afr[i] = *reinterpret_cast<const bf16x8*>(&As[ar*32 + (ksg^((ar>>1)&3))*8]);
    }
    #pragma unroll
    for(int j=0;j<4;j++){
      int br = wn*64+j*16+lr;
      bfr[j] = *reinterpret_cast<const bf16x8*>(&Bs[br*32 + (ksg^((br>>1)&3))*8]);
    }
    #pragma unroll
    for(int i=0;i<4;i++)
      #pragma unroll
      for(int j=0;j<4;j++)
        acc[i][j] = __builtin_amdgcn_mfma_f32_16x16x32_bf16(afr[i], bfr[j], acc[i][j], 0, 0, 0);
    __syncthreads();
  }
  const int hi = lane >> 4, lo = lane & 15;
  #pragma unroll
  for(int i=0;i<4;i++)
    #pragma unroll
    for(int j=0;j<4;j++)
      #pragma unroll
      for(int r=0;r<4;r++){
        int row = row0 + wm*64 + i*16 + 4*hi + r;
        int col = col0 + wn*64 + j*16 + lo;
        if(col < N) C[(size_t)row*ldc + col] = cvt_bf16(acc[i][j][r]);
      }
}

// out_proj GEMM, gload_lds staging + fused flip-add epilogue
__global__ __launch_bounds__(256) void k_mgo(
    const u16* __restrict__ A, const u16* __restrict__ BT,
    float* __restrict__ H, int flip)
{
  const int N = 512, K = 1024;
  __shared__ u16 As[128*32];
  __shared__ u16 Bs[128*32];
  const int tid = threadIdx.x;
  const int row0 = blockIdx.y*128, col0 = blockIdx.x*128;
  const int lane = tid & 63, wave = tid >> 6;
  const int wm = wave >> 1, wn = wave & 1;
  const int lr = lane & 15, ksg = (lane >> 4);
  const int srow = lane >> 2;
  const int slot = lane & 3;
  f32x4 acc[4][4];
  #pragma unroll
  for(int i=0;i<4;i++)
    #pragma unroll
    for(int j=0;j<4;j++) acc[i][j] = (f32x4){0.f,0.f,0.f,0.f};
  for(int k0=0;k0<K;k0+=32){
    #pragma unroll
    for(int i=0;i<2;i++){
      int seg = wave*2 + i;
      int row = seg*16 + srow;
      int kk  = slot ^ ((row>>1)&3);
      const u16* ga = A + (size_t)(row0+row)*K + k0 + kk*8;
      __builtin_amdgcn_global_load_lds(
        (const __attribute__((address_space(1))) void*)ga,
        (__attribute__((address_space(3))) void*)&As[seg*512], 16, 0, 0);
      int bcol = col0 + row; if(bcol > N-1) bcol = N-1;
      const u16* gb = BT + (size_t)bcol*K + k0 + kk*8;
      __builtin_amdgcn_global_load_lds(
        (const __attribute__((address_space(1))) void*)gb,
        (__attribute__((address_space(3))) void*)&Bs[seg*512], 16, 0, 0);
    }
    __syncthreads();
    bf16x8 afr[4], bfr[4];
    #pragma unroll
    for(int i=0;i<4;i++){
      int ar = wm*64+i*16+lr;
      afr[i] = *reinterpret_cast<const bf16x8*>(&As[ar*32 + (ksg^((ar>>1)&3))*8]);
    }
    #pragma unroll
    for(int j=0;j<4;j++){
      int br = wn*64+j*16+lr;
      bfr[j] = *reinterpret_cast<const bf16x8*>(&Bs[br*32 + (ksg^((br>>1)&3))*8]);
    }
    #pragma unroll
    for(int i=0;i<4;i++)
      #pragma unroll
      for(int j=0;j<4;j++)
        acc[i][j] = __builtin_amdgcn_mfma_f32_16x16x32_bf16(afr[i], bfr[j], acc[i][j], 0, 0, 0);
    __syncthreads();
  }
  const int hi = lane >> 4, lo = lane & 15;
  #pragma unroll
  for(int i=0;i<4;i++)
    #pragma unroll
    for(int j=0;j<4;j++)
      #pragma unroll
      for(int r=0;r<4;r++){
        int row = row0 + wm*64 + i*16 + 4*hi + r;
        int col = col0 + wn*64 + j*16 + lo;
        if(col < N){
          int b = row >> 11, l = row & (SEQL-1);
          int sl = flip ? (SEQL-1-l) : l;
          size_t ci = (size_t)(b*SEQL + sl)*DM + col;
          H[ci] += acc[i][j][r];
        }
      }
}

// batched variant: verified core + z-strided base offsets only
__global__ __launch_bounds__(256) void k_mgb(
    const u16* __restrict__ A0, const u16* __restrict__ BT0,
    float* __restrict__ C0, int M, int N, int K, int lda, int ldb, int ldc,
    long sAz, long sBz, long sCo, long sCi, int shC)
{
  const int z = blockIdx.z;
  const u16* A  = A0  + (size_t)z*sAz;
  const u16* BT = BT0 + (size_t)z*sBz;
  float* C = C0 + (size_t)(z>>shC)*sCo + (size_t)(z & ((1<<shC)-1))*sCi;
  __shared__ uint4 As4[128*5];
  __shared__ uint4 Bs4[128*5];
  const int tid = threadIdx.x;
  const int row0 = blockIdx.y*128, col0 = blockIdx.x*128;
  const int lane = tid & 63, wave = tid >> 6;
  const int wm = wave >> 1, wn = wave & 1;
  const int lr = lane & 15, ksg = (lane >> 4);
  f32x4 acc[4][4];
  #pragma unroll
  for(int i=0;i<4;i++)
    #pragma unroll
    for(int j=0;j<4;j++) acc[i][j] = (f32x4){0.f,0.f,0.f,0.f};
  for(int k0=0;k0<K;k0+=32){
    #pragma unroll
    for(int i=0;i<2;i++){
      int t2 = tid + i*256;
      int rr = t2 >> 2, sg = (t2 & 3);
      uint4 av = *reinterpret_cast<const uint4*>(A + (size_t)(row0+rr)*lda + k0 + sg*8);
      uint4 bv = {0u,0u,0u,0u};
      if(col0+rr < N) bv = *reinterpret_cast<const uint4*>(BT + (size_t)(col0+rr)*ldb + k0 + sg*8);
      As4[rr*5 + sg] = av;
      Bs4[rr*5 + sg] = bv;
    }
    __syncthreads();
    bf16x8 afr[4], bfr[4];
    #pragma unroll
    for(int i=0;i<4;i++) afr[i] = *reinterpret_cast<const bf16x8*>(&As4[(wm*64+i*16+lr)*5 + ksg]);
    #pragma unroll
    for(int j=0;j<4;j++) bfr[j] = *reinterpret_cast<const bf16x8*>(&Bs4[(wn*64+j*16+lr)*5 + ksg]);
    #pragma unroll
    for(int i=0;i<4;i++)
      #pragma unroll
      for(int j=0;j<4;j++)
        acc[i][j] = __builtin_amdgcn_mfma_f32_16x16x32_bf16(afr[i], bfr[j], acc[i][j], 0, 0, 0);
    __syncthreads();
  }
  const int hi = lane >> 4, lo = lane & 15;
  #pragma unroll
  for(int i=0;i<4;i++)
    #pragma unroll
    for(int j=0;j<4;j++)
      #pragma unroll
      for(int r=0;r<4;r++){
        int row = row0 + wm*64 + i*16 + 4*hi + r;
        int col = col0 + wn*64 + j*16 + lo;
        if(col < N) C[(size_t)row*ldc + col] = acc[i][j][r];
      }
}

// FUSED Y_diag + Y_off + gate (ZBh bf16; native cvt in staging)
__global__ __launch_bounds__(256) void k_mgf(
    const float* __restrict__ Sf, const float* __restrict__ ACUM,
    const u16* __restrict__ XdT, const u16* __restrict__ Cb0,
    const u16* __restrict__ PV0, const float* __restrict__ XCp,
    const u16* __restrict__ ZBh, const float* __restrict__ Dp,
    float* __restrict__ Y)
{
  const int z = blockIdx.z;
  const int h = z & 15, bc = z >> 4;
  const int b = bc >> 3, c = bc & 7;
  const float* Az = Sf + (size_t)bc*65536;
  const float* Acp = ACUM + (size_t)z*256;
  const u16* BT1 = XdT + (size_t)z*16384;
  const u16* A2  = Cb0 + (size_t)bc*16384;
  const u16* BT2 = PV0 + (size_t)bc*65536 + (size_t)h*4096;
  __shared__ uint4 As4[128*5];
  __shared__ uint4 Bs4[128*5];
  __shared__ float AcS[256];
  const int tid = threadIdx.x;
  AcS[tid] = Acp[tid];
  __syncthreads();
  const int row0 = blockIdx.y*128;
  const int lane = tid & 63, wave = tid >> 6;
  const int wm = wave >> 1, wn = wave & 1;
  const int lr = lane & 15, ksg = (lane >> 4);
  f32x4 acc[4][4];
  #pragma unroll
  for(int i=0;i<4;i++)
    #pragma unroll
    for(int j=0;j<4;j++) acc[i][j] = (f32x4){0.f,0.f,0.f,0.f};
  for(int k0=0;k0<256;k0+=32){
    #pragma unroll
    for(int i=0;i<2;i++){
      int t2 = tid + i*256;
      int rr = t2 >> 2, sg = (t2 & 3);
      int l = row0 + rr;
      int sbase = k0 + sg*8;
      float4 v0 = *reinterpret_cast<const float4*>(Az + (size_t)l*256 + sbase);
      float4 v1 = *reinterpret_cast<const float4*>(Az + (size_t)l*256 + sbase + 4);
      float acl = AcS[l];
      float vv[8] = {v0.x,v0.y,v0.z,v0.w,v1.x,v1.y,v1.z,v1.w};
      u16 gbuf[8];
      #pragma unroll
      for(int e=0;e<8;e++){
        int s = sbase + e;
        float g = 0.f;
        if(s <= l) g = __expf(acl - AcS[s]) * vv[e];
        gbuf[e] = cvtb(g);
      }
      As4[rr*5 + sg] = *reinterpret_cast<uint4*>(gbuf);
      uint4 bv = {0u,0u,0u,0u};
      if(rr < 64) bv = *reinterpret_cast<const uint4*>(BT1 + (size_t)rr*256 + sbase);
      Bs4[rr*5 + sg] = bv;
    }
    __syncthreads();
    bf16x8 afr[4], bfr[4];
    #pragma unroll
    for(int i=0;i<4;i++) afr[i] = *reinterpret_cast<const bf16x8*>(&As4[(wm*64+i*16+lr)*5 + ksg]);
    #pragma unroll
    for(int j=0;j<4;j++) bfr[j] = *reinterpret_cast<const bf16x8*>(&Bs4[(wn*64+j*16+lr)*5 + ksg]);
    #pragma unroll
    for(int i=0;i<4;i++)
      #pragma unroll
      for(int j=0;j<4;j++)
        acc[i][j] = __builtin_amdgcn_mfma_f32_16x16x32_bf16(afr[i], bfr[j], acc[i][j], 0, 0, 0);
    __syncthreads();
  }
  for(int k0=0;k0<64;k0+=32){
    #pragma unroll
    for(int i=0;i<2;i++){
      int t2 = tid + i*256;
      int rr = t2 >> 2, sg = (t2 & 3);
      int sbase = k0 + sg*8;
      uint4 raw = *reinterpret_cast<const uint4*>(A2 + (size_t)(row0+rr)*64 + sbase);
      const u16* rp = reinterpret_cast<const u16*>(&raw);
      float scale = __expf(AcS[row0+rr]);
      u16 buf[8];
      #pragma unroll
      for(int e=0;e<8;e++) buf[e] = cvtb(bf2f(rp[e]) * scale);
      As4[rr*5 + sg] = *reinterpret_cast<uint4*>(buf);
      uint4 bv = {0u,0u,0u,0u};
      if(rr < 64) bv = *reinterpret_cast<const uint4*>(BT2 + (size_t)rr*64 + sbase);
      Bs4[rr*5 + sg] = bv;
    }
    __syncthreads();
    bf16x8 afr[4], bfr[4];
    #pragma unroll
    for(int i=0;i<4;i++) afr[i] = *reinterpret_cast<const bf16x8*>(&As4[(wm*64+i*16+lr)*5 + ksg]);
    #pragma unroll
    for(int j=0;j<4;j++) bfr[j] = *reinterpret_cast<const bf16x8*>(&Bs4[(wn*64+j*16+lr)*5 + ksg]);
    #pragma unroll
    for(int i=0;i<4;i++)
      #pragma unroll
      for(int j=0;j<4;j++)
        acc[i][j] = __builtin_amdgcn_mfma_f32_16x16x32_bf16(afr[i], bfr[j], acc[i][j], 0, 0, 0);
    __syncthreads();
  }
  const int hi = lane >> 4, lo = lane & 15;
  #pragma unroll
  for(int i=0;i<4;i++)
    #pragma unroll
    for(int j=0;j<4;j++)
      #pragma unroll
      for(int r=0;r<4;r++){
        int row = row0 + wm*64 + i*16 + 4*hi + r;
        int col = wn*64 + j*16 + lo;
        if(col < 64){
          int g = b*SEQL + c*CKS + row;
          int ch = h*HD + col;
          float xh = XCp[(size_t)g*CVD + ch];
          float zg = bf2f(ZBh[(size_t)g*DIP + ch]);
          float v = acc[i][j][r] + Dp[h]*xh;
          float sig = 1.f/(1.f+expf(-zg));
          Y[(size_t)g*DIN + ch] = v * (zg*sig);
        }
      }
}

// states via MFMA (native cvt in staging)
__global__ __launch_bounds__(256) void k_mgs(
    const u16* __restrict__ XdT, const u16* __restrict__ BTc,
    const float* __restrict__ ACUM, float* __restrict__ ST)
{
  const int z = blockIdx.z;
  const int bc = z >> 4;
  const u16* Ap = XdT + (size_t)z*16384;
  const u16* BT = BTc + (size_t)bc*16384;
  float* Cp = ST + (size_t)z*4096;
  __shared__ uint4 As4[128*5];
  __shared__ uint4 Bs4[128*5];
  __shared__ float decS[256];
  const int tid = threadIdx.x;
  {
    const float* Acp = ACUM + (size_t)z*256;
    decS[tid] = __expf(Acp[255] - Acp[tid]);
  }
  __syncthreads();
  const int lane = tid & 63, wave = tid >> 6;
  const int wm = wave >> 1, wn = wave & 1;
  const int lr = lane & 15, ksg = (lane >> 4);
  f32x4 acc[4][4];
  #pragma unroll
  for(int i=0;i<4;i++)
    #pragma unroll
    for(int j=0;j<4;j++) acc[i][j] = (f32x4){0.f,0.f,0.f,0.f};
  for(int k0=0;k0<256;k0+=32){
    #pragma unroll
    for(int i=0;i<2;i++){
      int t2 = tid + i*256;
      int rr = t2 >> 2, sg = (t2 & 3);
      int sbase = k0 + sg*8;
      uint4 av = {0u,0u,0u,0u};
      if(rr < 64){
        uint4 raw = *reinterpret_cast<const uint4*>(Ap + (size_t)rr*256 + sbase);
        const u16* rp = reinterpret_cast<const u16*>(&raw);
        u16 buf[8];
        #pragma unroll
        for(int e=0;e<8;e++) buf[e] = cvtb(bf2f(rp[e]) * decS[sbase+e]);
        av = *reinterpret_cast<uint4*>(buf);
      }
      As4[rr*5 + sg] = av;
      uint4 bv = {0u,0u,0u,0u};
      if(rr < 64) bv = *reinterpret_cast<const uint4*>(BT + (size_t)rr*256 + sbase);
      Bs4[rr*5 + sg] = bv;
    }
    __syncthreads();
    bf16x8 afr[4], bfr[4];
    #pragma unroll
    for(int i=0;i<4;i++) afr[i] = *reinterpret_cast<const bf16x8*>(&As4[(wm*64+i*16+lr)*5 + ksg]);
    #pragma unroll
    for(int j=0;j<4;j++) bfr[j] = *reinterpret_cast<const bf16x8*>(&Bs4[(wn*64+j*16+lr)*5 + ksg]);
    #pragma unroll
    for(int i=0;i<4;i++)
      #pragma unroll
      for(int j=0;j<4;j++)
        acc[i][j] = __builtin_amdgcn_mfma_f32_16x16x32_bf16(afr[i], bfr[j], acc[i][j], 0, 0, 0);
    __syncthreads();
  }
  const int hi = lane >> 4, lo = lane & 15;
  #pragma unroll
  for(int i=0;i<4;i++)
    #pragma unroll
    for(int j=0;j<4;j++)
      #pragma unroll
      for(int r=0;r<4;r++){
        int row = wm*64 + i*16 + 4*hi + r;
        int col = wn*64 + j*16 + lo;
        if(row < 64 && col < 64) Cp[(size_t)row*64 + col] = acc[i][j][r];
      }
}

// batched attention GEMM
__global__ __launch_bounds__(256) void k_mgab(
    const u16* __restrict__ A0, const u16* __restrict__ BT0,
    float* __restrict__ C0, u16* __restrict__ Cb0,
    int M, int N, int K, int lda, int ldb, int ldc,
    long sAo, long sAi, long sBo, long sBi, long sCo, long sCi, float scale)
{
  const int z = blockIdx.z;
  const u16* A  = A0  + (size_t)(z>>2)*sAo + (size_t)(z&3)*sAi;
  const u16* BT = BT0 + (size_t)(z>>2)*sBo + (size_t)(z&3)*sBi;
  const size_t offC = (size_t)(z>>2)*sCo + (size_t)(z&3)*sCi;
  __shared__ uint4 As4[128*5];
  __shared__ uint4 Bs4[128*5];
  const int tid = threadIdx.x;
  const int row0 = blockIdx.y*128, col0 = blockIdx.x*128;
  const int lane = tid & 63, wave = tid >> 6;
  const int wm = wave >> 1, wn = wave & 1;
  const int lr = lane & 15, ksg = (lane >> 4);
  f32x4 acc[4][4];
  #pragma unroll
  for(int i=0;i<4;i++)
    #pragma unroll
    for(int j=0;j<4;j++) acc[i][j] = (f32x4){0.f,0.f,0.f,0.f};
  for(int k0=0;k0<K;k0+=32){
    #pragma unroll
    for(int i=0;i<2;i++){
      int t2 = tid + i*256;
      int rr = t2 >> 2, sg = (t2 & 3);
      uint4 av = *reinterpret_cast<const uint4*>(A + (size_t)(row0+rr)*lda + k0 + sg*8);
      uint4 bv = {0u,0u,0u,0u};
      if(col0+rr < N) bv = *reinterpret_cast<const uint4*>(BT + (size_t)(col0+rr)*ldb + k0 + sg*8);
      As4[rr*5 + sg] = av;
      Bs4[rr*5 + sg] = bv;
    }
    __syncthreads();
    bf16x8 afr[4], bfr[4];
    #pragma unroll
    for(int i=0;i<4;i++) afr[i] = *reinterpret_cast<const bf16x8*>(&As4[(wm*64+i*16+lr)*5 + ksg]);
    #pragma unroll
    for(int j=0;j<4;j++) bfr[j] = *reinterpret_cast<const bf16x8*>(&Bs4[(wn*64+j*16+lr)*5 + ksg]);
    #pragma unroll
    for(int i=0;i<4;i++)
      #pragma unroll
      for(int j=0;j<4;j++)
        acc[i][j] = __builtin_amdgcn_mfma_f32_16x16x32_bf16(afr[i], bfr[j], acc[i][j], 0, 0, 0);
    __syncthreads();
  }
  const int hi = lane >> 4, lo = lane & 15;
  #pragma unroll
  for(int i=0;i<4;i++)
    #pragma unroll
    for(int j=0;j<4;j++)
      #pragma unroll
      for(int r=0;r<4;r++){
        int row = row0 + wm*64 + i*16 + 4*hi + r;
        int col = col0 + wn*64 + j*16 + lo;
        if(col < N){
          float v = acc[i][j][r] * scale;
          size_t ci = offC + (size_t)row*ldc + col;
          if(C0) C0[ci] = v;
          else   Cb0[ci] = cvt_bf16(v);
        }
      }
}

// verified core + arithmetic epilogue (attention projections)
__global__ __launch_bounds__(256) void k_mge(
    const u16* __restrict__ A, const u16* __restrict__ BT,
    const float* __restrict__ bias, const float* __restrict__ res,
    float* __restrict__ C, u16* __restrict__ Cbf,
    int M, int N, int K, int lda, int ldb, int ldc, float scale, int act)
{
  __shared__ uint4 As4[128*5];
  __shared__ uint4 Bs4[128*5];
  const int tid = threadIdx.x;
  const int row0 = blockIdx.y*128, col0 = blockIdx.x*128;
  const int lane = tid & 63, wave = tid >> 6;
  const int wm = wave >> 1, wn = wave & 1;
  const int lr = lane & 15, ksg = (lane >> 4);
  f32x4 acc[4][4];
  #pragma unroll
  for(int i=0;i<4;i++)
    #pragma unroll
    for(int j=0;j<4;j++) acc[i][j] = (f32x4){0.f,0.f,0.f,0.f};
  for(int k0=0;k0<K;k0+=32){
    #pragma unroll
    for(int i=0;i<2;i++){
      int t2 = tid + i*256;
      int rr = t2 >> 2, sg = (t2 & 3);
      uint4 av = *reinterpret_cast<const uint4*>(A + (size_t)(row0+rr)*lda + k0 + sg*8);
      uint4 bv = {0u,0u,0u,0u};
      if(col0+rr < N) bv = *reinterpret_cast<const uint4*>(BT + (size_t)(col0+rr)*ldb + k0 + sg*8);
      As4[rr*5 + sg] = av;
      Bs4[rr*5 + sg] = bv;
    }
    __syncthreads();
    bf16x8 afr[4], bfr[4];
    #pragma unroll
    for(int i=0;i<4;i++) afr[i] = *reinterpret_cast<const bf16x8*>(&As4[(wm*64+i*16+lr)*5 + ksg]);
    #pragma unroll
    for(int j=0;j<4;j++) bfr[j] = *reinterpret_cast<const bf16x8*>(&Bs4[(wn*64+j*16+lr)*5 + ksg]);
    #pragma unroll
    for(int i=0;i<4;i++)
      #pragma unroll
      for(int j=0;j<4;j++)
        acc[i][j] = __builtin_amdgcn_mfma_f32_16x16x32_bf16(afr[i], bfr[j], acc[i][j], 0, 0, 0);
    __syncthreads();
  }
  const int hi = lane >> 4, lo = lane & 15;
  #pragma unroll
  for(int i=0;i<4;i++)
    #pragma unroll
    for(int j=0;j<4;j++)
      #pragma unroll
      for(int r=0;r<4;r++){
        int row = row0 + wm*64 + i*16 + 4*hi + r;
        int col = col0 + wn*64 + j*16 + lo;
        if(col < N){
          float v = acc[i][j][r];
          if(bias) v += bias[col];
          v *= scale;
          if(act==1) v = 0.5f*v*(1.f+erff(v*0.70710678118654752f));
          size_t ci = (size_t)row*ldc + col;
          if(res) v += res[ci];
          if(C) C[ci] = v;
          else  Cbf[ci] = cvt_bf16(v);
        }
      }
}

// in-place row softmax over 1024 bf16
__global__ void k_sm(u16* __restrict__ S){
  size_t row = blockIdx.x;
  u16* p = S + row*1024;
  int tid = threadIdx.x;
  ushort4 u = reinterpret_cast<ushort4*>(p)[tid];
  float v0=bf2f(u.x), v1=bf2f(u.y), v2=bf2f(u.z), v3=bf2f(u.w);
  float m = fmaxf(fmaxf(v0,v1),fmaxf(v2,v3));
  __shared__ float red[256];
  red[tid]=m; __syncthreads();
  for(int o=128;o>0;o>>=1){ if(tid<o) red[tid]=fmaxf(red[tid],red[tid+o]); __syncthreads(); }
  m = red[0]; __syncthreads();
  v0=__expf(v0-m); v1=__expf(v1-m); v2=__expf(v2-m); v3=__expf(v3-m);
  float s = v0+v1+v2+v3;
  red[tid]=s; __syncthreads();
  for(int o=128;o>0;o>>=1){ if(tid<o) red[tid]+=red[tid+o]; __syncthreads(); }
  float inv = 1.f/red[0];
  ushort4 o4; o4.x=cvt_bf16(v0*inv); o4.y=cvt_bf16(v1*inv); o4.z=cvt_bf16(v2*inv); o4.w=cvt_bf16(v3*inv);
  reinterpret_cast<ushort4*>(p)[tid] = o4;
}

// ---------------- mamba pieces (ZBh bf16) ----------------
__global__ void k_conv4(const u16* __restrict__ ZBh, const float* __restrict__ cw,
                        const float* __restrict__ cb, float* __restrict__ XC){
  int i = blockIdx.x*256 + threadIdx.x;
  if(i >= BS*512*CVD) return;
  int cch = i % CVD;
  int lq = (i / CVD) & 511;
  int b = i / (CVD*512);
  int l0 = lq*4;
  float w[7];
  #pragma unroll
  for(int t=0;t<7;t++){
    int sl = l0 - 3 + t;
    w[t] = (sl >= 0) ? bf2f(ZBh[(size_t)(b*SEQL+sl)*DIP + DIN + cch]) : 0.f;
  }
  float c0 = cw[cch*4+0], c1 = cw[cch*4+1], c2 = cw[cch*4+2], c3 = cw[cch*4+3];
  float bb2 = cb[cch];
  #pragma unroll
  for(int j=0;j<4;j++){
    float v = bb2 + w[j]*c0 + w[j+1]*c1 + w[j+2]*c2 + w[j+3]*c3;
    float sig = 1.f/(1.f+expf(-v));
    XC[(size_t)(b*SEQL + l0 + j)*CVD + cch] = v*sig;
  }
}

__global__ void k_dt(const u16* __restrict__ ZBh, const float* __restrict__ dtb,
                     const float* __restrict__ Alog, float* __restrict__ DT,
                     float* __restrict__ DA){
  int i = blockIdx.x*256 + threadIdx.x;
  if(i >= BS*SEQL*NH) return;
  int h = i & (NH-1);
  int row = i >> 4;
  float raw = bf2f(ZBh[(size_t)row*DIP + (DIN+CVD) + h]) + dtb[h];
  float dt = fmaxf(raw,0.f) + log1pf(expf(-fabsf(raw)));
  DT[i] = dt;
  DA[i] = dt * (-expf(Alog[h]));
}

__global__ void k_acum(const float* __restrict__ DA, float* __restrict__ ACUM,
                       float* __restrict__ CDEC){
  int blk = blockIdx.x;
  int h = blk & 15, c = (blk>>4)&7, b = blk>>7;
  int l = threadIdx.x;
  __shared__ float s[256];
  int gl = c*CKS + l;
  s[l] = DA[(size_t)(b*SEQL + gl)*NH + h];
  __syncthreads();
  for(int off=1; off<256; off<<=1){
    float v = (l>=off) ? s[l-off] : 0.f;
    __syncthreads();
    s[l] += v;
    __syncthreads();
  }
  ACUM[(size_t)blk*CKS + l] = s[l];
  if(l==255) CDEC[blk] = expf(s[255]);
}

// extract B,C as bf16 [8192][64]
__global__ void k_bc(const float* __restrict__ XC, u16* __restrict__ Bbf,
                     u16* __restrict__ Cbf){
  int i = blockIdx.x*256 + threadIdx.x;
  if(i >= NROWS*DST) return;
  int g = i >> 6, n = i & 63;
  Bbf[i] = cvt_bf16(XC[(size_t)g*CVD + DIN + n]);
  Cbf[i] = cvt_bf16(XC[(size_t)g*CVD + DIN + DST + n]);
}

// inter-chunk scan, writing bf16 PREV directly (bit-identical to scan+cvt)
__global__ void k_scan(const float* __restrict__ ST, const float* __restrict__ CDEC,
                       u16* __restrict__ PREVbf){
  int i = blockIdx.x*256 + threadIdx.x;
  if(i >= BS*NH*4096) return;
  int pn = i & 4095;
  int h = (i>>12) & 15;
  int b = i >> 16;
  float run = 0.f;
  for(int c=0;c<8;c++){
    size_t idx = (size_t)((b*8+c)*16+h)*4096 + pn;
    PREVbf[idx] = cvt_bf16(run);
    run = run*CDEC[(b*8+c)*16+h] + ST[idx];
  }
}

// ---------------- attention helpers ----------------
__global__ void k_extract(const float* __restrict__ HF, float* __restrict__ QIN,
                          float* __restrict__ CIN){
  int i = blockIdx.x*256 + threadIdx.x;
  if(i >= BS*1024*DM) return;
  int d = i & (DM-1);
  int q = (i>>9) & 1023;
  int b = i >> 19;
  QIN[i] = HF[(size_t)(b*SEQL + 1024 + q)*DM + d];
  CIN[i] = HF[(size_t)(b*SEQL + q)*DM + d];
}

// ---------------- host ----------------
extern "C" void kernel_launch(void* const* d_in, const int* in_sizes, int n_in,
                              void* d_out, int out_size, void* d_ws, size_t ws_size,
                              hipStream_t stream) {
  (void)in_sizes; (void)n_in; (void)out_size; (void)ws_size;
  const float* x_enc     = (const float*)d_in[0];
  const float* in_proj_w = (const float*)d_in[2];
  const float* conv_w    = (const float*)d_in[3];
  const float* conv_b    = (const float*)d_in[4];
  const float* dt_bias   = (const float*)d_in[5];
  const float* A_log     = (const float*)d_in[6];
  const float* D_param   = (const float*)d_in[7];
  const float* gnorm_w   = (const float*)d_in[8];
  const float* out_proj_w= (const float*)d_in[9];
  const float* norm_w    = (const float*)d_in[10];
  const float* norm_b    = (const float*)d_in[11];
  const float* normf_w   = (const float*)d_in[12];
  const float* normf_b   = (const float*)d_in[13];
  const float* ca_nq_w   = (const float*)d_in[14];
  const float* ca_nq_b   = (const float*)d_in[15];
  const float* ca_nkv_w  = (const float*)d_in[16];
  const float* ca_nkv_b  = (const float*)d_in[17];
  const float* ca_qw     = (const float*)d_in[18];
  const float* ca_kw     = (const float*)d_in[19];
  const float* ca_vw     = (const float*)d_in[20];
  const float* ca_ow     = (const float*)d_in[21];
  const float* ca_qb     = (const float*)d_in[22];
  const float* ca_kb     = (const float*)d_in[23];
  const float* ca_vb     = (const float*)d_in[24];
  const float* ca_ob     = (const float*)d_in[25];
  const float* qp_w      = (const float*)d_in[26];
  const float* qp_b      = (const float*)d_in[27];
  const float* cp_w      = (const float*)d_in[28];
  const float* cp_b      = (const float*)d_in[29];
  const float* dec1_w    = (const float*)d_in[30];
  const float* dec1_b    = (const float*)d_in[31];
  const float* dec2_w    = (const float*)d_in[32];
  const float* dec2_b    = (const float*)d_in[33];

  float* W = (float*)d_ws;
  size_t off = 0;
  auto alloc = [&](size_t n){ float* pp = W + off; off += n; return pp; };
  float* RES  = alloc((size_t)NTOK);
  float* H    = alloc((size_t)NTOK);
  float* HN   = alloc((size_t)NTOK);
  float* HNF  = alloc((size_t)NTOK);
  float* ZB   = alloc((size_t)NROWS*DIP);        // region reused: ZBh bf16 uses half
  float* XC   = alloc((size_t)NROWS*CVD);
  float* DT   = alloc((size_t)NROWS*NH);
  float* DA   = alloc((size_t)NROWS*NH);
  float* ACUM = alloc((size_t)BS*NC*NH*CKS);
  float* CDEC = alloc((size_t)BS*NC*NH);
  float* Y    = alloc((size_t)NROWS*DIN);
  float* ST   = alloc((size_t)BS*NC*NH*4096);
  float* PREV = alloc((size_t)BS*NC*NH*4096);
  float* HF2  = alloc((size_t)NTOK);
  float* HF   = alloc((size_t)NTOK);
  (void)PREV;
  float* YD   = HF2;

  u16* ZBh    = (u16*)ZB;                        // bf16 in_proj output [8192][2192]
  // mamba staging aliases (proven lifetimes):
  u16* Ubf    = (u16*)HF;
  u16* WinTc  = (u16*)(HF + 2097152);
  u16* WoutTc = (u16*)(HF + 2097152 + 561152);
  u16* Ybf    = (u16*)HNF;
  // SSD staging (disjoint within HNF):
  u16*   Bbf    = (u16*)HNF;
  u16*   Cbf    = Bbf + 524288;
  float* Sf     = HNF + 524288;
  u16*   BTc    = (u16*)(HNF + 2621440);
  u16*   PREVbf = (u16*)(HNF + 2883584);
  u16*   XdTg   = (u16*)YD;

  const int TPB = 256;
  const int gTok = (NTOK+TPB-1)/TPB;
  dim3 tb(32,8);

  hipMemcpyAsync(RES, x_enc, (size_t)NTOK*4, hipMemcpyDeviceToDevice, stream);

  for(int layer=0; layer<2; ++layer){
    if(layer>0) k_add_flip<<<gTok,TPB,0,stream>>>(RES, H, 0);
    k_ln<<<NROWS,TPB,0,stream>>>(RES, norm_w + layer*DM, norm_b + layer*DM, HN);
    hipMemsetAsync(H, 0, (size_t)NTOK*4, stream);
    for(int dir=0; dir<2; ++dir){
      int idx = layer*2 + dir;
      const float* cw   = conv_w   + (size_t)idx*CVD*4;
      const float* cb   = conv_b   + (size_t)idx*CVD;
      const float* dtb  = dt_bias  + (size_t)idx*NH;
      const float* Alog = A_log    + (size_t)idx*NH;
      const float* Dp   = D_param  + (size_t)idx*NH;
      const float* gw   = gnorm_w  + (size_t)idx*DIN;

      if(dir==0){
        k_cvt<<<(NTOK/4+TPB-1)/TPB,TPB,0,stream>>>(HN, Ubf, NTOK/4);
      }else{
        k_flip<<<gTok,TPB,0,stream>>>(HNF, HN);
        k_cvt<<<(NTOK/4+TPB-1)/TPB,TPB,0,stream>>>(HNF, Ubf, NTOK/4);
      }
      k_wt2<<<dim3(69,16),tb,0,stream>>>(in_proj_w + (size_t)idx*DM*DIP, WinTc, 512, 2192, 2192);
      k_mgc<<<dim3(18,64),256,0,stream>>>(Ubf, WinTc, ZBh, 8192, 2192, 512, 512, 512, 2192);

      k_conv4<<<(BS*512*CVD+TPB-1)/TPB,TPB,0,stream>>>(ZBh, cw, cb, XC);
      k_dt<<<(BS*SEQL*NH+TPB-1)/TPB,TPB,0,stream>>>(ZBh, dtb, Alog, DT, DA);
      k_acum<<<BS*NC*NH,256,0,stream>>>(DA, ACUM, CDEC);

      // ---- SSD pre-computation ----
      k_bc<<<(NROWS*DST+TPB-1)/TPB,TPB,0,stream>>>(XC, Bbf, Cbf);
      k_mgb<<<dim3(2,2,32),256,0,stream>>>(Cbf, Bbf, Sf,
            256, 256, 64, 64, 64, 256, 16384, 16384, 65536, 0, 0);
      k_xdtt<<<dim3(2,8,512),tb,0,stream>>>(XC, DT, XdTg);
      k_btc<<<dim3(2,8,32),tb,0,stream>>>(Bbf, BTc);
      k_mgs<<<dim3(1,1,512),256,0,stream>>>(XdTg, BTc, ACUM, ST);
      k_scan<<<(BS*NH*4096+TPB-1)/TPB,TPB,0,stream>>>(ST, CDEC, PREVbf);
      // ---- fused Y_diag + Y_off + gate (write-only Y) ----
      k_mgf<<<dim3(1,2,512),256,0,stream>>>(Sf, ACUM, XdTg, Cbf, PREVbf, XC, ZBh, Dp, Y);

      // ---- RMSNorm -> bf16 directly ----
      k_rmsb<<<NROWS,256,0,stream>>>(Y, gw, Ybf);
      k_wt2<<<dim3(16,32),tb,0,stream>>>(out_proj_w + (size_t)idx*DIN*DM, WoutTc, 1024, 512, 512);
      // ---- out_proj with fused flip-add into H ----
      k_mgo<<<dim3(4,64),256,0,stream>>>(Ybf, WoutTc, H, dir);
    }
  }
  k_add_flip<<<gTok,TPB,0,stream>>>(RES, H, 0);
  k_ln<<<NROWS,TPB,0,stream>>>(RES, normf_w, normf_b, HF);

  // ================= attention head — MFMA (batched) =================
  float* P0   = ZB;
  float* QIN  = P0 + 0;
  float* CIN  = P0 + 2097152;
  float* QPb  = P0 + 4194304;
  float* CPb  = P0 + 6291456;
  float* QN   = P0 + 8388608;
  float* CN   = P0 + 10485760;
  float* AO   = P0 + 12582912;
  float* O1   = P0 + 14680064;
  float* D1   = P0 + 16777216;
  float* VV   = D1;
  u16* U0     = (u16*)(P0 + 20971520);
  u16* Qbf    = U0 + 0;
  u16* Cbf2   = U0 + 2097152;
  u16* QNbf   = U0 + 4194304;
  u16* CNbf   = U0 + 6291456;
  u16* QQbf   = U0 + 8388608;
  u16* KKbf   = U0 + 10485760;
  u16* VTbf   = U0 + 12582912;
  u16* AObf   = U0 + 14680064;
  u16* O1bf   = U0 + 16777216;
  u16* qpT    = U0 + 18874368;
  u16* cpT    = qpT + 262144;
  u16* qwT    = qpT + 524288;
  u16* kwT    = qpT + 786432;
  u16* vwT    = qpT + 1048576;
  u16* owT    = qpT + 1310720;
  u16* dec1T  = qpT + 1572864;
  u16* Pbf    = qpT + 2097152;

  const int M2 = BS*1024;
  k_extract<<<(BS*1024*DM+TPB-1)/TPB,TPB,0,stream>>>(HF, QIN, CIN);
  k_cvt<<<(2097152/4+TPB-1)/TPB,TPB,0,stream>>>(QIN, Qbf, 2097152/4);
  k_cvt<<<(2097152/4+TPB-1)/TPB,TPB,0,stream>>>(CIN, Cbf2, 2097152/4);
  k_wt2<<<dim3(16,16),tb,0,stream>>>(qp_w, qpT, 512, 512, 512);
  k_wt2<<<dim3(16,16),tb,0,stream>>>(cp_w, cpT, 512, 512, 512);
  k_wt2<<<dim3(16,16),tb,0,stream>>>(ca_qw, qwT, 512, 512, 512);
  k_wt2<<<dim3(16,16),tb,0,stream>>>(ca_kw, kwT, 512, 512, 512);
  k_wt2<<<dim3(16,16),tb,0,stream>>>(ca_vw, vwT, 512, 512, 512);
  k_wt2<<<dim3(16,16),tb,0,stream>>>(ca_ow, owT, 512, 512, 512);
  k_wt2<<<dim3(32,16),tb,0,stream>>>(dec1_w, dec1T, 512, 1024, 1024);

  k_mge<<<dim3(4,32),256,0,stream>>>(Qbf, qpT, qp_b, nullptr, QPb, nullptr,
                                     M2, 512, 512, 512, 512, 512, 1.f, 0);
  k_mge<<<dim3(4,32),256,0,stream>>>(Cbf2, cpT, cp_b, nullptr, CPb, nullptr,
                                     M2, 512, 512, 512, 512, 512, 1.f, 0);
  k_ln<<<M2,TPB,0,stream>>>(QPb, ca_nq_w, ca_nq_b, QN);
  k_ln<<<M2,TPB,0,stream>>>(CPb, ca_nkv_w, ca_nkv_b, CN);
  k_cvt<<<(2097152/4+TPB-1)/TPB,TPB,0,stream>>>(QN, QNbf, 2097152/4);
  k_cvt<<<(2097152/4+TPB-1)/TPB,TPB,0,stream>>>(CN, CNbf, 2097152/4);
  k_mge<<<dim3(4,32),256,0,stream>>>(QNbf, qwT, ca_qb, nullptr, nullptr, QQbf,
                                     M2, 512, 512, 512, 512, 512, 1.f, 0);
  k_mge<<<dim3(4,32),256,0,stream>>>(CNbf, kwT, ca_kb, nullptr, nullptr, KKbf,
                                     M2, 512, 512, 512, 512, 512, 1.f, 0);
  k_mge<<<dim3(4,32),256,0,stream>>>(CNbf, vwT, ca_vb, nullptr, VV, nullptr,
                                     M2, 512, 512, 512, 512, 512, 1.f, 0);
  k_vtb<<<dim3(4,32,16),tb,0,stream>>>(VV, VTbf);
  const float scl = 0.088388347648318447f;
  k_mgab<<<dim3(8,8,16),256,0,stream>>>(QQbf, KKbf, nullptr, Pbf,
        1024, 1024, 128, 512, 512, 1024,
        524288, 128, 524288, 128, 4194304, 1048576, scl);
  k_sm<<<16384,256,0,stream>>>(Pbf);
  k_mgab<<<dim3(1,8,16),256,0,stream>>>(Pbf, VTbf, AO, nullptr,
        1024, 128, 1024, 1024, 1024, 512,
        4194304, 1048576, 524288, 131072, 524288, 128, 1.f);
  k_cvt<<<(2097152/4+TPB-1)/TPB,TPB,0,stream>>>(AO, AObf, 2097152/4);
  k_mge<<<dim3(4,32),256,0,stream>>>(AObf, owT, ca_ob, QPb, O1, nullptr,
                                     M2, 512, 512, 512, 512, 512, 1.f, 0);
  k_cvt<<<(2097152/4+TPB-1)/TPB,TPB,0,stream>>>(O1, O1bf, 2097152/4);
  k_mge<<<dim3(8,32),256,0,stream>>>(O1bf, dec1T, dec1_b, nullptr, D1, nullptr,
                                     M2, 1024, 512, 512, 512, 1024, 1.f, 1);
  k_dec2<<<M2,256,0,stream>>>(D1, dec2_w, dec2_b, (float*)d_out);
}